// Round 1
// baseline (1030.573 us; speedup 1.0000x reference)
//
#include <hip/hip_runtime.h>
#include <math.h>

#define N_NODES 100000
#define N_EDGES 1600000
#define D 128
#define L_LAYERS 3
#define P_STATS 7
#define B_GRAPHS 64
#define BN_EPS 1e-5f
#define NEG_SLOPE 0.2f

// ---------------- CSR build ----------------

__global__ void zero_kernel(int* __restrict__ deg) {
    int i = blockIdx.x * blockDim.x + threadIdx.x;
    if (i < N_NODES) deg[i] = 0;
}

__global__ void count_kernel(const int* __restrict__ dst, int* __restrict__ deg) {
    int e = blockIdx.x * blockDim.x + threadIdx.x;
    if (e < N_EDGES) atomicAdd(&deg[dst[e]], 1);
}

// chunk = 2048 elements per block (256 threads x 8)
__global__ void scan1_kernel(const int* __restrict__ deg, int* __restrict__ incl,
                             int* __restrict__ bsum) {
    __shared__ int s[256];
    const int tid = threadIdx.x;
    const int base = blockIdx.x * 2048;
    int v[8];
    int sum = 0;
    const int idx0 = base + tid * 8;
#pragma unroll
    for (int i = 0; i < 8; ++i) {
        int idx = idx0 + i;
        int d = (idx < N_NODES) ? deg[idx] : 0;
        sum += d;
        v[i] = sum;
    }
    s[tid] = sum;
    __syncthreads();
    // Hillis-Steele inclusive scan over 256 partials
    for (int off = 1; off < 256; off <<= 1) {
        int t = (tid >= off) ? s[tid - off] : 0;
        __syncthreads();
        s[tid] += t;
        __syncthreads();
    }
    int prev = (tid > 0) ? s[tid - 1] : 0;
#pragma unroll
    for (int i = 0; i < 8; ++i) {
        int idx = idx0 + i;
        if (idx < N_NODES) incl[idx] = v[i] + prev;
    }
    if (tid == 255) bsum[blockIdx.x] = s[255];
}

__global__ void scan2_kernel(int* __restrict__ bsum, int nb) {
    if (threadIdx.x == 0 && blockIdx.x == 0) {
        int run = 0;
        for (int i = 0; i < nb; ++i) { int t = bsum[i]; bsum[i] = run; run += t; }
    }
}

__global__ void scan3_kernel(const int* __restrict__ deg, const int* __restrict__ incl,
                             const int* __restrict__ bsum, int* __restrict__ start,
                             int* __restrict__ cursor) {
    int i = blockIdx.x * blockDim.x + threadIdx.x;
    if (i < N_NODES) {
        int inc = incl[i] + bsum[i >> 11];  // 2048 chunk
        int st = inc - deg[i];
        start[i] = st;
        cursor[i] = st;
    }
    if (i == 0) start[N_NODES] = N_EDGES;
}

__global__ void scatter_kernel(const int* __restrict__ src, const int* __restrict__ dst,
                               int* __restrict__ cursor, int* __restrict__ csr_src) {
    int e = blockIdx.x * blockDim.x + threadIdx.x;
    if (e < N_EDGES) {
        int pos = atomicAdd(&cursor[dst[e]], 1);
        csr_src[pos] = src[e];
    }
}

// ---------------- per-graph stat projections ----------------
// gproj[l][b][j] = sum_p nan2num(gs[b][p]) * statWs[l][p][j] + statBs[l][j]
__global__ void gproj_kernel(const float* __restrict__ gs, const float* __restrict__ statWs,
                             const float* __restrict__ statBs, float* __restrict__ gproj) {
    int b = blockIdx.x;
    int l = blockIdx.y;
    int j = threadIdx.x;
    float acc = statBs[l * D + j];
#pragma unroll
    for (int p = 0; p < P_STATS; ++p) {
        float g = gs[b * P_STATS + p];
        if (g != g) g = -100.0f;  // nan_to_num
        acc += g * statWs[(l * P_STATS + p) * D + j];
    }
    gproj[(l * B_GRAPHS + b) * D + j] = acc;
}

// ---------------- aggregation: m = h + segment_sum(h[src], dst) ----------------
// 8 nodes per block, 32 lanes (float4) per node.
__global__ __launch_bounds__(256) void agg_kernel(const float* __restrict__ h,
                                                  const int* __restrict__ start,
                                                  const int* __restrict__ csr_src,
                                                  float* __restrict__ m) {
    int node = blockIdx.x * 8 + (threadIdx.x >> 5);
    int c4 = threadIdx.x & 31;
    if (node >= N_NODES) return;
    const float4* h4 = (const float4*)h;
    float4 acc = h4[node * 32 + c4];
    int s = start[node];
    int e = start[node + 1];
    for (int k = s; k < e; ++k) {
        int sn = csr_src[k];
        float4 v = h4[sn * 32 + c4];
        acc.x += v.x; acc.y += v.y; acc.z += v.z; acc.w += v.w;
    }
    ((float4*)m)[node * 32 + c4] = acc;
}

// ---------------- fused MLP (two GEMMs + activations + BN + stat add) ----------------
// 64 rows x 128 cols per block, 256 threads, thread tile 4 rows x 8 cols.
// FINAL=true: out = m @ W1 + b1 only (fc_out).
template <bool FINAL>
__global__ __launch_bounds__(256, 2) void mlp_kernel(
    const float* __restrict__ m, const float* __restrict__ W1, const float* __restrict__ b1,
    const float* __restrict__ gamma, const float* __restrict__ beta,
    const float* __restrict__ mean, const float* __restrict__ var,
    const float* __restrict__ W2, const float* __restrict__ b2,
    const float* __restrict__ gproj, const int* __restrict__ batch,
    float* __restrict__ out) {
    __shared__ float sm[64 * 132];
    __shared__ float sy[64 * 132];
    const int tid = threadIdx.x;
    const int tr = tid >> 4;  // 0..15
    const int tc = tid & 15;  // 0..15
    const int row0 = blockIdx.x * 64;
    const int c0 = tc * 8;

    // load 64x128 m tile
    {
        const float4* m4 = (const float4*)m;
#pragma unroll
        for (int t = 0; t < 8; ++t) {
            int q = tid + t * 256;  // 0..2047
            int r = q >> 5, cc = q & 31;
            int node = row0 + r;
            float4 v = make_float4(0.f, 0.f, 0.f, 0.f);
            if (node < N_NODES) v = m4[node * 32 + cc];
            float* d = &sm[r * 132 + cc * 4];
            d[0] = v.x; d[1] = v.y; d[2] = v.z; d[3] = v.w;
        }
    }
    __syncthreads();

    float acc[4][8];
    {
#pragma unroll
        for (int u = 0; u < 8; ++u) {
            float bb = b1[c0 + u];
            acc[0][u] = bb; acc[1][u] = bb; acc[2][u] = bb; acc[3][u] = bb;
        }
    }
    // GEMM1: acc += sm @ W1
    {
        const float4* W4 = (const float4*)W1;
        for (int k = 0; k < 128; ++k) {
            float a0 = sm[(tr) * 132 + k];
            float a1 = sm[(tr + 16) * 132 + k];
            float a2 = sm[(tr + 32) * 132 + k];
            float a3 = sm[(tr + 48) * 132 + k];
            float4 w0 = W4[k * 32 + tc * 2];
            float4 w1 = W4[k * 32 + tc * 2 + 1];
            float w[8] = {w0.x, w0.y, w0.z, w0.w, w1.x, w1.y, w1.z, w1.w};
#pragma unroll
            for (int u = 0; u < 8; ++u) {
                acc[0][u] += a0 * w[u];
                acc[1][u] += a1 * w[u];
                acc[2][u] += a2 * w[u];
                acc[3][u] += a3 * w[u];
            }
        }
    }

    if (FINAL) {
#pragma unroll
        for (int q = 0; q < 4; ++q) {
            int node = row0 + tr + 16 * q;
            if (node < N_NODES) {
                float4* o = (float4*)&out[node * D + c0];
                o[0] = make_float4(acc[q][0], acc[q][1], acc[q][2], acc[q][3]);
                o[1] = make_float4(acc[q][4], acc[q][5], acc[q][6], acc[q][7]);
            }
        }
        return;
    }

    // LeakyReLU -> BN (eval) -> sy
    {
        float sc[8], mn[8], bt[8];
#pragma unroll
        for (int u = 0; u < 8; ++u) {
            int c = c0 + u;
            sc[u] = gamma[c] * rsqrtf(var[c] + BN_EPS);
            mn[u] = mean[c];
            bt[u] = beta[c];
        }
#pragma unroll
        for (int q = 0; q < 4; ++q) {
            int r = tr + 16 * q;
#pragma unroll
            for (int u = 0; u < 8; ++u) {
                float v = acc[q][u];
                v = (v > 0.f) ? v : NEG_SLOPE * v;
                v = (v - mn[u]) * sc[u] + bt[u];
                sy[r * 132 + c0 + u] = v;
            }
        }
    }
    __syncthreads();

    float acc2[4][8];
    {
#pragma unroll
        for (int u = 0; u < 8; ++u) {
            float bb = b2[c0 + u];
            acc2[0][u] = bb; acc2[1][u] = bb; acc2[2][u] = bb; acc2[3][u] = bb;
        }
    }
    // GEMM2: acc2 += sy @ W2
    {
        const float4* W4 = (const float4*)W2;
        for (int k = 0; k < 128; ++k) {
            float a0 = sy[(tr) * 132 + k];
            float a1 = sy[(tr + 16) * 132 + k];
            float a2 = sy[(tr + 32) * 132 + k];
            float a3 = sy[(tr + 48) * 132 + k];
            float4 w0 = W4[k * 32 + tc * 2];
            float4 w1 = W4[k * 32 + tc * 2 + 1];
            float w[8] = {w0.x, w0.y, w0.z, w0.w, w1.x, w1.y, w1.z, w1.w};
#pragma unroll
            for (int u = 0; u < 8; ++u) {
                acc2[0][u] += a0 * w[u];
                acc2[1][u] += a1 * w[u];
                acc2[2][u] += a2 * w[u];
                acc2[3][u] += a3 * w[u];
            }
        }
    }
    // LeakyReLU + gproj[batch] add -> out
#pragma unroll
    for (int q = 0; q < 4; ++q) {
        int node = row0 + tr + 16 * q;
        if (node < N_NODES) {
            int b = batch[node];
            const float* gp = &gproj[b * D + c0];
            float r0[8];
#pragma unroll
            for (int u = 0; u < 8; ++u) {
                float v = acc2[q][u];
                v = (v > 0.f) ? v : NEG_SLOPE * v;
                r0[u] = v + gp[u];
            }
            float4* o = (float4*)&out[node * D + c0];
            o[0] = make_float4(r0[0], r0[1], r0[2], r0[3]);
            o[1] = make_float4(r0[4], r0[5], r0[6], r0[7]);
        }
    }
}

// ---------------- launch ----------------

extern "C" void kernel_launch(void* const* d_in, const int* in_sizes, int n_in,
                              void* d_out, int out_size, void* d_ws, size_t ws_size,
                              hipStream_t stream) {
    const float* x = (const float*)d_in[0];
    const int* ei = (const int*)d_in[1];
    const int* src = ei;
    const int* dst = ei + N_EDGES;
    const int* batch = (const int*)d_in[2];
    const float* gs = (const float*)d_in[3];
    const float* W1s = (const float*)d_in[4];
    const float* b1s = (const float*)d_in[5];
    const float* gammas = (const float*)d_in[6];
    const float* betas = (const float*)d_in[7];
    const float* means = (const float*)d_in[8];
    const float* vars = (const float*)d_in[9];
    const float* W2s = (const float*)d_in[10];
    const float* b2s = (const float*)d_in[11];
    const float* statWs = (const float*)d_in[12];
    const float* statBs = (const float*)d_in[13];
    const float* fcW = (const float*)d_in[14];
    const float* fcB = (const float*)d_in[15];
    float* out = (float*)d_out;

    char* ws = (char*)d_ws;
    auto alloc = [&](size_t bytes) {
        char* p = ws;
        ws += (bytes + 255) / 256 * 256;
        return p;
    };
    int* deg = (int*)alloc(N_NODES * sizeof(int));
    int* incl = (int*)alloc(N_NODES * sizeof(int));
    int* bsum = (int*)alloc(64 * sizeof(int));
    int* start = (int*)alloc((N_NODES + 1) * sizeof(int));
    int* cursor = (int*)alloc(N_NODES * sizeof(int));
    int* csr_src = (int*)alloc(N_EDGES * sizeof(int));
    float* gproj = (float*)alloc((size_t)L_LAYERS * B_GRAPHS * D * sizeof(float));
    float* m_tmp = (float*)alloc((size_t)N_NODES * D * sizeof(float));
    float* h_tmp = (float*)alloc((size_t)N_NODES * D * sizeof(float));

    const int nscan = (N_NODES + 2047) / 2048;  // 49

    // CSR build (dst does not change across layers -> build once)
    zero_kernel<<<(N_NODES + 255) / 256, 256, 0, stream>>>(deg);
    count_kernel<<<(N_EDGES + 255) / 256, 256, 0, stream>>>(dst, deg);
    scan1_kernel<<<nscan, 256, 0, stream>>>(deg, incl, bsum);
    scan2_kernel<<<1, 64, 0, stream>>>(bsum, nscan);
    scan3_kernel<<<(N_NODES + 255) / 256, 256, 0, stream>>>(deg, incl, bsum, start, cursor);
    scatter_kernel<<<(N_EDGES + 255) / 256, 256, 0, stream>>>(src, dst, cursor, csr_src);

    // per-graph stat projections for all layers
    gproj_kernel<<<dim3(B_GRAPHS, L_LAYERS), D, 0, stream>>>(gs, statWs, statBs, gproj);

    const int agg_blocks = (N_NODES + 7) / 8;
    const int mlp_blocks = (N_NODES + 63) / 64;

    // layer 0: x -> h_tmp
    agg_kernel<<<agg_blocks, 256, 0, stream>>>(x, start, csr_src, m_tmp);
    mlp_kernel<false><<<mlp_blocks, 256, 0, stream>>>(
        m_tmp, W1s + 0 * D * D, b1s + 0 * D, gammas + 0 * D, betas + 0 * D, means + 0 * D,
        vars + 0 * D, W2s + 0 * D * D, b2s + 0 * D, gproj + 0 * B_GRAPHS * D, batch, h_tmp);
    // layer 1: h_tmp -> out (as temp)
    agg_kernel<<<agg_blocks, 256, 0, stream>>>(h_tmp, start, csr_src, m_tmp);
    mlp_kernel<false><<<mlp_blocks, 256, 0, stream>>>(
        m_tmp, W1s + 1 * D * D, b1s + 1 * D, gammas + 1 * D, betas + 1 * D, means + 1 * D,
        vars + 1 * D, W2s + 1 * D * D, b2s + 1 * D, gproj + 1 * B_GRAPHS * D, batch, out);
    // layer 2: out -> h_tmp
    agg_kernel<<<agg_blocks, 256, 0, stream>>>(out, start, csr_src, m_tmp);
    mlp_kernel<false><<<mlp_blocks, 256, 0, stream>>>(
        m_tmp, W1s + 2 * D * D, b1s + 2 * D, gammas + 2 * D, betas + 2 * D, means + 2 * D,
        vars + 2 * D, W2s + 2 * D * D, b2s + 2 * D, gproj + 2 * B_GRAPHS * D, batch, h_tmp);
    // fc_out: h_tmp -> out
    mlp_kernel<true><<<mlp_blocks, 256, 0, stream>>>(
        h_tmp, fcW, fcB, nullptr, nullptr, nullptr, nullptr, nullptr, nullptr, nullptr, nullptr,
        out);
}

// Round 2
// 710.439 us; speedup vs baseline: 1.4506x; 1.4506x over previous
//
#include <hip/hip_runtime.h>
#include <math.h>

#define N_NODES 100000
#define N_EDGES 1600000
#define D 128
#define L_LAYERS 3
#define P_STATS 7
#define B_GRAPHS 64
#define BN_EPS 1e-5f
#define NEG_SLOPE 0.2f

typedef __attribute__((ext_vector_type(8))) short bf16x8;
typedef __attribute__((ext_vector_type(4))) float f32x4;

static __device__ __forceinline__ short f2bf(float f) {
    union { float f; unsigned u; } v;
    v.f = f;
    unsigned r = v.u + 0x7fffu + ((v.u >> 16) & 1u);  // RNE
    return (short)(r >> 16);
}

// ---------------- CSR build ----------------

__global__ void zero_kernel(int* __restrict__ deg) {
    int i = blockIdx.x * blockDim.x + threadIdx.x;
    if (i < N_NODES) deg[i] = 0;
}

__global__ void count_kernel(const int* __restrict__ dst, int* __restrict__ deg) {
    int e = blockIdx.x * blockDim.x + threadIdx.x;
    if (e < N_EDGES) atomicAdd(&deg[dst[e]], 1);
}

__global__ void scan1_kernel(const int* __restrict__ deg, int* __restrict__ incl,
                             int* __restrict__ bsum) {
    __shared__ int s[256];
    const int tid = threadIdx.x;
    const int base = blockIdx.x * 2048;
    int v[8];
    int sum = 0;
    const int idx0 = base + tid * 8;
#pragma unroll
    for (int i = 0; i < 8; ++i) {
        int idx = idx0 + i;
        int d = (idx < N_NODES) ? deg[idx] : 0;
        sum += d;
        v[i] = sum;
    }
    s[tid] = sum;
    __syncthreads();
    for (int off = 1; off < 256; off <<= 1) {
        int t = (tid >= off) ? s[tid - off] : 0;
        __syncthreads();
        s[tid] += t;
        __syncthreads();
    }
    int prev = (tid > 0) ? s[tid - 1] : 0;
#pragma unroll
    for (int i = 0; i < 8; ++i) {
        int idx = idx0 + i;
        if (idx < N_NODES) incl[idx] = v[i] + prev;
    }
    if (tid == 255) bsum[blockIdx.x] = s[255];
}

__global__ void scan2_kernel(int* __restrict__ bsum, int nb) {
    if (threadIdx.x == 0 && blockIdx.x == 0) {
        int run = 0;
        for (int i = 0; i < nb; ++i) { int t = bsum[i]; bsum[i] = run; run += t; }
    }
}

__global__ void scan3_kernel(const int* __restrict__ deg, const int* __restrict__ incl,
                             const int* __restrict__ bsum, int* __restrict__ start,
                             int* __restrict__ cursor) {
    int i = blockIdx.x * blockDim.x + threadIdx.x;
    if (i < N_NODES) {
        int inc = incl[i] + bsum[i >> 11];
        int st = inc - deg[i];
        start[i] = st;
        cursor[i] = st;
    }
    if (i == 0) start[N_NODES] = N_EDGES;
}

__global__ void scatter_kernel(const int* __restrict__ src, const int* __restrict__ dst,
                               int* __restrict__ cursor, int* __restrict__ csr_src) {
    int e = blockIdx.x * blockDim.x + threadIdx.x;
    if (e < N_EDGES) {
        int pos = atomicAdd(&cursor[dst[e]], 1);
        csr_src[pos] = src[e];
    }
}

// ---------------- per-graph stat projections ----------------
__global__ void gproj_kernel(const float* __restrict__ gs, const float* __restrict__ statWs,
                             const float* __restrict__ statBs, float* __restrict__ gproj) {
    int b = blockIdx.x;
    int l = blockIdx.y;
    int j = threadIdx.x;
    float acc = statBs[l * D + j];
#pragma unroll
    for (int p = 0; p < P_STATS; ++p) {
        float g = gs[b * P_STATS + p];
        if (g != g) g = -100.0f;
        acc += g * statWs[(l * P_STATS + p) * D + j];
    }
    gproj[(l * B_GRAPHS + b) * D + j] = acc;
}

// ---------------- weight convert: W[k][n] f32 -> Wt[n][k] bf16 ----------------
// matrices 0..2 = W1s, 3..5 = W2s, 6 = fcW
__global__ void wconv_kernel(const float* __restrict__ W1s, const float* __restrict__ W2s,
                             const float* __restrict__ fcW, short* __restrict__ wt) {
    int mid = blockIdx.y;
    const float* src = (mid < 3) ? (W1s + mid * D * D)
                                 : ((mid < 6) ? (W2s + (mid - 3) * D * D) : fcW);
    short* dstm = wt + mid * D * D;
    int i = blockIdx.x * 256 + threadIdx.x;  // 0..16383
    int k = i >> 7, n = i & 127;
    dstm[n * D + k] = f2bf(src[i]);
}

// ---------------- aggregation: m = h + segment_sum(h[src], dst) -> bf16 ----------------
__global__ __launch_bounds__(256) void agg_kernel(const float* __restrict__ h,
                                                  const int* __restrict__ start,
                                                  const int* __restrict__ csr_src,
                                                  short* __restrict__ m_bf) {
    int node = blockIdx.x * 8 + (threadIdx.x >> 5);
    int c4 = threadIdx.x & 31;
    if (node >= N_NODES) return;
    const float4* h4 = (const float4*)h;
    float4 acc = h4[node * 32 + c4];
    int s = start[node];
    int e = start[node + 1];
    for (int k = s; k < e; ++k) {
        int sn = csr_src[k];
        float4 v = h4[sn * 32 + c4];
        acc.x += v.x; acc.y += v.y; acc.z += v.z; acc.w += v.w;
    }
    short4 pk;
    pk.x = f2bf(acc.x); pk.y = f2bf(acc.y); pk.z = f2bf(acc.z); pk.w = f2bf(acc.w);
    ((short4*)m_bf)[node * 32 + c4] = pk;
}

// ---------------- MFMA MLP ----------------
// Block: 128 nodes x 128 features, 256 threads = 4 waves (2 node-halves x 2 feat-halves).
// Computes Y^T = mfma(Wt_frag, m_frag): C col = node (lane&15), C row = feature.
// FINAL: out = m @ W + b only. OUTBF16: write bf16 (layer 2, feeds fc_out).
template <bool FINAL, bool OUTBF16>
__global__ __launch_bounds__(256, 2) void mlp_mfma_kernel(
    const short* __restrict__ m_bf,   // [N][128] bf16
    const short* __restrict__ W1t,    // [n][k] bf16
    const float* __restrict__ b1,
    const float* __restrict__ gamma, const float* __restrict__ beta,
    const float* __restrict__ mean, const float* __restrict__ var,
    const short* __restrict__ W2t,
    const float* __restrict__ b2,
    const float* __restrict__ gproj, const int* __restrict__ batch,
    float* __restrict__ outf, short* __restrict__ outb) {
    __shared__ short sy[128 * 128];  // 32KB, XOR-swizzled rows
    __shared__ float sB1[128], sSc[128], sSb[128], sB2[128];

    const int tid = threadIdx.x;
    const int wid = tid >> 6;
    const int lane = tid & 63;
    const int lr = lane & 15;
    const int lk = lane >> 4;

    if (tid < 128) {
        sB1[tid] = b1[tid];
        if (!FINAL) {
            float sc = gamma[tid] * rsqrtf(var[tid] + BN_EPS);
            sSc[tid] = sc;
            sSb[tid] = beta[tid] - mean[tid] * sc;
            sB2[tid] = b2[tid];
        }
    }
    __syncthreads();

    const int nodeBase = blockIdx.x * 128 + (wid & 1) * 64;
    const int featBase = (wid >> 1) * 64;
    const int nlBase = (wid & 1) * 64;

    // clamped node ids for A/B loads (stores are guarded)
    int nIdx[4];
#pragma unroll
    for (int mt = 0; mt < 4; ++mt) {
        int n = nodeBase + mt * 16 + lr;
        nIdx[mt] = (n < N_NODES) ? n : (N_NODES - 1);
    }

    // ---- W1 fragments (A operand) ----
    bf16x8 wf[4][4];
#pragma unroll
    for (int ft = 0; ft < 4; ++ft)
#pragma unroll
        for (int kt = 0; kt < 4; ++kt)
            wf[ft][kt] = *(const bf16x8*)&W1t[(featBase + ft * 16 + lr) * D + kt * 32 + lk * 8];

    f32x4 acc[4][4];
#pragma unroll
    for (int ft = 0; ft < 4; ++ft)
#pragma unroll
        for (int mt = 0; mt < 4; ++mt)
            acc[ft][mt] = (f32x4)(0.0f);

    // ---- GEMM1 ----
#pragma unroll
    for (int kt = 0; kt < 4; ++kt) {
        bf16x8 mf[4];
#pragma unroll
        for (int mt = 0; mt < 4; ++mt)
            mf[mt] = *(const bf16x8*)&m_bf[nIdx[mt] * D + kt * 32 + lk * 8];
#pragma unroll
        for (int ft = 0; ft < 4; ++ft)
#pragma unroll
            for (int mt = 0; mt < 4; ++mt)
                acc[ft][mt] = __builtin_amdgcn_mfma_f32_16x16x32_bf16(wf[ft][kt], mf[mt],
                                                                      acc[ft][mt], 0, 0, 0);
    }

    if (FINAL) {
#pragma unroll
        for (int mt = 0; mt < 4; ++mt) {
            int node = nodeBase + mt * 16 + lr;
            if (node < N_NODES) {
#pragma unroll
                for (int ft = 0; ft < 4; ++ft) {
                    int f0 = featBase + ft * 16 + lk * 4;
                    float4 o;
                    o.x = acc[ft][mt][0] + sB1[f0 + 0];
                    o.y = acc[ft][mt][1] + sB1[f0 + 1];
                    o.z = acc[ft][mt][2] + sB1[f0 + 2];
                    o.w = acc[ft][mt][3] + sB1[f0 + 3];
                    *(float4*)&outf[node * D + f0] = o;
                }
            }
        }
        return;
    }

    // ---- bias + LeakyReLU + BN -> bf16 -> LDS (swizzled) ----
#pragma unroll
    for (int ft = 0; ft < 4; ++ft) {
        int f0 = featBase + ft * 16 + lk * 4;
#pragma unroll
        for (int mt = 0; mt < 4; ++mt) {
            int nl = nlBase + mt * 16 + lr;
            short4 pk;
#pragma unroll
            for (int r = 0; r < 4; ++r) {
                float v = acc[ft][mt][r] + sB1[f0 + r];
                v = (v > 0.f) ? v : NEG_SLOPE * v;
                v = v * sSc[f0 + r] + sSb[f0 + r];
                ((short*)&pk)[r] = f2bf(v);
            }
            int byteoff = nl * 256 + f0 * 2;
            byteoff ^= (nl & 7) << 4;
            *(short4*)((char*)sy + byteoff) = pk;
        }
    }
    __syncthreads();

    // ---- W2 fragments ----
#pragma unroll
    for (int ft = 0; ft < 4; ++ft)
#pragma unroll
        for (int kt = 0; kt < 4; ++kt)
            wf[ft][kt] = *(const bf16x8*)&W2t[(featBase + ft * 16 + lr) * D + kt * 32 + lk * 8];

#pragma unroll
    for (int ft = 0; ft < 4; ++ft)
#pragma unroll
        for (int mt = 0; mt < 4; ++mt)
            acc[ft][mt] = (f32x4)(0.0f);

    // ---- GEMM2 (B from swizzled LDS) ----
#pragma unroll
    for (int kt = 0; kt < 4; ++kt) {
        bf16x8 yf[4];
#pragma unroll
        for (int mt = 0; mt < 4; ++mt) {
            int nl = nlBase + mt * 16 + lr;
            int byteoff = nl * 256 + kt * 64 + lk * 16;
            byteoff ^= (nl & 7) << 4;
            yf[mt] = *(const bf16x8*)((char*)sy + byteoff);
        }
#pragma unroll
        for (int ft = 0; ft < 4; ++ft)
#pragma unroll
            for (int mt = 0; mt < 4; ++mt)
                acc[ft][mt] = __builtin_amdgcn_mfma_f32_16x16x32_bf16(wf[ft][kt], yf[mt],
                                                                      acc[ft][mt], 0, 0, 0);
    }

    // ---- bias + LeakyReLU + gproj add -> store ----
#pragma unroll
    for (int mt = 0; mt < 4; ++mt) {
        int node = nodeBase + mt * 16 + lr;
        if (node >= N_NODES) continue;
        int bid = batch[node];
#pragma unroll
        for (int ft = 0; ft < 4; ++ft) {
            int f0 = featBase + ft * 16 + lk * 4;
            const float4 gp = *(const float4*)&gproj[bid * D + f0];
            float v0 = acc[ft][mt][0] + sB2[f0 + 0]; v0 = (v0 > 0.f) ? v0 : NEG_SLOPE * v0; v0 += gp.x;
            float v1 = acc[ft][mt][1] + sB2[f0 + 1]; v1 = (v1 > 0.f) ? v1 : NEG_SLOPE * v1; v1 += gp.y;
            float v2 = acc[ft][mt][2] + sB2[f0 + 2]; v2 = (v2 > 0.f) ? v2 : NEG_SLOPE * v2; v2 += gp.z;
            float v3 = acc[ft][mt][3] + sB2[f0 + 3]; v3 = (v3 > 0.f) ? v3 : NEG_SLOPE * v3; v3 += gp.w;
            if (OUTBF16) {
                short4 pk;
                pk.x = f2bf(v0); pk.y = f2bf(v1); pk.z = f2bf(v2); pk.w = f2bf(v3);
                *(short4*)&outb[node * D + f0] = pk;
            } else {
                *(float4*)&outf[node * D + f0] = make_float4(v0, v1, v2, v3);
            }
        }
    }
}

// ---------------- launch ----------------

extern "C" void kernel_launch(void* const* d_in, const int* in_sizes, int n_in,
                              void* d_out, int out_size, void* d_ws, size_t ws_size,
                              hipStream_t stream) {
    const float* x = (const float*)d_in[0];
    const int* ei = (const int*)d_in[1];
    const int* src = ei;
    const int* dst = ei + N_EDGES;
    const int* batch = (const int*)d_in[2];
    const float* gs = (const float*)d_in[3];
    const float* W1s = (const float*)d_in[4];
    const float* b1s = (const float*)d_in[5];
    const float* gammas = (const float*)d_in[6];
    const float* betas = (const float*)d_in[7];
    const float* means = (const float*)d_in[8];
    const float* vars = (const float*)d_in[9];
    const float* W2s = (const float*)d_in[10];
    const float* b2s = (const float*)d_in[11];
    const float* statWs = (const float*)d_in[12];
    const float* statBs = (const float*)d_in[13];
    const float* fcW = (const float*)d_in[14];
    const float* fcB = (const float*)d_in[15];
    float* out = (float*)d_out;

    char* ws = (char*)d_ws;
    auto alloc = [&](size_t bytes) {
        char* p = ws;
        ws += (bytes + 255) / 256 * 256;
        return p;
    };
    int* deg = (int*)alloc(N_NODES * sizeof(int));
    int* incl = (int*)alloc(N_NODES * sizeof(int));
    int* bsum = (int*)alloc(64 * sizeof(int));
    int* start = (int*)alloc((N_NODES + 1) * sizeof(int));
    int* cursor = (int*)alloc(N_NODES * sizeof(int));
    int* csr_src = (int*)alloc(N_EDGES * sizeof(int));
    float* gproj = (float*)alloc((size_t)L_LAYERS * B_GRAPHS * D * sizeof(float));
    short* wt = (short*)alloc((size_t)7 * D * D * sizeof(short));
    short* m_bf = (short*)alloc((size_t)N_NODES * D * sizeof(short));
    short* hb_bf = (short*)alloc((size_t)N_NODES * D * sizeof(short));
    float* h_tmp = (float*)alloc((size_t)N_NODES * D * sizeof(float));

    const int nscan = (N_NODES + 2047) / 2048;

    zero_kernel<<<(N_NODES + 255) / 256, 256, 0, stream>>>(deg);
    count_kernel<<<(N_EDGES + 255) / 256, 256, 0, stream>>>(dst, deg);
    scan1_kernel<<<nscan, 256, 0, stream>>>(deg, incl, bsum);
    scan2_kernel<<<1, 64, 0, stream>>>(bsum, nscan);
    scan3_kernel<<<(N_NODES + 255) / 256, 256, 0, stream>>>(deg, incl, bsum, start, cursor);
    scatter_kernel<<<(N_EDGES + 255) / 256, 256, 0, stream>>>(src, dst, cursor, csr_src);

    gproj_kernel<<<dim3(B_GRAPHS, L_LAYERS), D, 0, stream>>>(gs, statWs, statBs, gproj);
    wconv_kernel<<<dim3(64, 7), 256, 0, stream>>>(W1s, W2s, fcW, wt);

    const int agg_blocks = (N_NODES + 7) / 8;
    const int mlp_blocks = (N_NODES + 127) / 128;

    // layer 0: x -> m_bf -> h_tmp (f32)
    agg_kernel<<<agg_blocks, 256, 0, stream>>>(x, start, csr_src, m_bf);
    mlp_mfma_kernel<false, false><<<mlp_blocks, 256, 0, stream>>>(
        m_bf, wt + 0 * D * D, b1s + 0 * D, gammas + 0 * D, betas + 0 * D, means + 0 * D,
        vars + 0 * D, wt + 3 * D * D, b2s + 0 * D, gproj + 0 * B_GRAPHS * D, batch, h_tmp, nullptr);
    // layer 1: h_tmp -> m_bf -> out (f32 temp)
    agg_kernel<<<agg_blocks, 256, 0, stream>>>(h_tmp, start, csr_src, m_bf);
    mlp_mfma_kernel<false, false><<<mlp_blocks, 256, 0, stream>>>(
        m_bf, wt + 1 * D * D, b1s + 1 * D, gammas + 1 * D, betas + 1 * D, means + 1 * D,
        vars + 1 * D, wt + 4 * D * D, b2s + 1 * D, gproj + 1 * B_GRAPHS * D, batch, out, nullptr);
    // layer 2: out -> m_bf -> hb_bf (bf16, only consumed by fc_out)
    agg_kernel<<<agg_blocks, 256, 0, stream>>>(out, start, csr_src, m_bf);
    mlp_mfma_kernel<false, true><<<mlp_blocks, 256, 0, stream>>>(
        m_bf, wt + 2 * D * D, b1s + 2 * D, gammas + 2 * D, betas + 2 * D, means + 2 * D,
        vars + 2 * D, wt + 5 * D * D, b2s + 2 * D, gproj + 2 * B_GRAPHS * D, batch, nullptr, hb_bf);
    // fc_out: hb_bf -> out (f32)
    mlp_mfma_kernel<true, false><<<mlp_blocks, 256, 0, stream>>>(
        hb_bf, wt + 6 * D * D, fcB, nullptr, nullptr, nullptr, nullptr, nullptr, nullptr, nullptr,
        batch, out, nullptr);
}

// Round 3
// 540.059 us; speedup vs baseline: 1.9083x; 1.3155x over previous
//
#include <hip/hip_runtime.h>
#include <math.h>

#define N_NODES 100000
#define N_EDGES 1600000
#define D 128
#define L_LAYERS 3
#define P_STATS 7
#define B_GRAPHS 64
#define BN_EPS 1e-5f
#define NEG_SLOPE 0.2f

typedef __attribute__((ext_vector_type(8))) short bf16x8;
typedef __attribute__((ext_vector_type(4))) float f32x4;

static __device__ __forceinline__ short f2bf(float f) {
    union { float f; unsigned u; } v;
    v.f = f;
    unsigned r = v.u + 0x7fffu + ((v.u >> 16) & 1u);  // RNE
    return (short)(r >> 16);
}

static __device__ __forceinline__ float bf2f(short s) {
    union { unsigned u; float f; } v;
    v.u = ((unsigned)(unsigned short)s) << 16;
    return v.f;
}

// ---------------- CSR build ----------------

__global__ void zero_kernel(int* __restrict__ deg) {
    int i = blockIdx.x * blockDim.x + threadIdx.x;
    if (i < N_NODES) deg[i] = 0;
}

__global__ void count_kernel(const int* __restrict__ dst, int* __restrict__ deg) {
    int e = blockIdx.x * blockDim.x + threadIdx.x;
    if (e < N_EDGES) atomicAdd(&deg[dst[e]], 1);
}

__global__ void scan1_kernel(const int* __restrict__ deg, int* __restrict__ incl,
                             int* __restrict__ bsum) {
    __shared__ int s[256];
    const int tid = threadIdx.x;
    const int base = blockIdx.x * 2048;
    int v[8];
    int sum = 0;
    const int idx0 = base + tid * 8;
#pragma unroll
    for (int i = 0; i < 8; ++i) {
        int idx = idx0 + i;
        int d = (idx < N_NODES) ? deg[idx] : 0;
        sum += d;
        v[i] = sum;
    }
    s[tid] = sum;
    __syncthreads();
    for (int off = 1; off < 256; off <<= 1) {
        int t = (tid >= off) ? s[tid - off] : 0;
        __syncthreads();
        s[tid] += t;
        __syncthreads();
    }
    int prev = (tid > 0) ? s[tid - 1] : 0;
#pragma unroll
    for (int i = 0; i < 8; ++i) {
        int idx = idx0 + i;
        if (idx < N_NODES) incl[idx] = v[i] + prev;
    }
    if (tid == 255) bsum[blockIdx.x] = s[255];
}

__global__ void scan2_kernel(int* __restrict__ bsum, int nb) {
    if (threadIdx.x == 0 && blockIdx.x == 0) {
        int run = 0;
        for (int i = 0; i < nb; ++i) { int t = bsum[i]; bsum[i] = run; run += t; }
    }
}

__global__ void scan3_kernel(const int* __restrict__ deg, const int* __restrict__ incl,
                             const int* __restrict__ bsum, int* __restrict__ start,
                             int* __restrict__ cursor) {
    int i = blockIdx.x * blockDim.x + threadIdx.x;
    if (i < N_NODES) {
        int inc = incl[i] + bsum[i >> 11];
        int st = inc - deg[i];
        start[i] = st;
        cursor[i] = st;
    }
    if (i == 0) start[N_NODES] = N_EDGES;
}

__global__ void scatter_kernel(const int* __restrict__ src, const int* __restrict__ dst,
                               int* __restrict__ cursor, int* __restrict__ csr_src) {
    int e = blockIdx.x * blockDim.x + threadIdx.x;
    if (e < N_EDGES) {
        int pos = atomicAdd(&cursor[dst[e]], 1);
        csr_src[pos] = src[e];
    }
}

// ---------------- per-graph stat projections ----------------
__global__ void gproj_kernel(const float* __restrict__ gs, const float* __restrict__ statWs,
                             const float* __restrict__ statBs, float* __restrict__ gproj) {
    int b = blockIdx.x;
    int l = blockIdx.y;
    int j = threadIdx.x;
    float acc = statBs[l * D + j];
#pragma unroll
    for (int p = 0; p < P_STATS; ++p) {
        float g = gs[b * P_STATS + p];
        if (g != g) g = -100.0f;
        acc += g * statWs[(l * P_STATS + p) * D + j];
    }
    gproj[(l * B_GRAPHS + b) * D + j] = acc;
}

// ---------------- weight convert: W[k][n] f32 -> Wt[n][k] bf16 ----------------
__global__ void wconv_kernel(const float* __restrict__ W1s, const float* __restrict__ W2s,
                             const float* __restrict__ fcW, short* __restrict__ wt) {
    int mid = blockIdx.y;
    const float* src = (mid < 3) ? (W1s + mid * D * D)
                                 : ((mid < 6) ? (W2s + (mid - 3) * D * D) : fcW);
    short* dstm = wt + mid * D * D;
    int i = blockIdx.x * 256 + threadIdx.x;
    int k = i >> 7, n = i & 127;
    dstm[n * D + k] = f2bf(src[i]);
}

// ---------------- x f32 -> bf16 ----------------
__global__ __launch_bounds__(256) void xconv_kernel(const float* __restrict__ x,
                                                    short* __restrict__ xb) {
    int i = blockIdx.x * 256 + threadIdx.x;  // one 8-elem chunk per thread
    const float4* x4 = (const float4*)x;
    float4 a = x4[i * 2], b = x4[i * 2 + 1];
    short s[8];
    s[0] = f2bf(a.x); s[1] = f2bf(a.y); s[2] = f2bf(a.z); s[3] = f2bf(a.w);
    s[4] = f2bf(b.x); s[5] = f2bf(b.y); s[6] = f2bf(b.z); s[7] = f2bf(b.w);
    *(bf16x8*)&xb[i * 8] = *(bf16x8*)s;
}

// ---------------- aggregation: m = h + segment_sum(h[src], dst), bf16 in/out ----------------
// 16 nodes per block, 16 lanes (bf16x8 = 16B) per node. 100000 % 16 == 0.
__global__ __launch_bounds__(256) void agg_kernel(const short* __restrict__ hb,
                                                  const int* __restrict__ start,
                                                  const int* __restrict__ csr_src,
                                                  short* __restrict__ m_bf) {
    int node = blockIdx.x * 16 + (threadIdx.x >> 4);
    int c8 = threadIdx.x & 15;
    const bf16x8* h8 = (const bf16x8*)hb;

    bf16x8 own = h8[node * 16 + c8];
    float acc[8];
#pragma unroll
    for (int i = 0; i < 8; ++i) acc[i] = bf2f(own[i]);

    int s = start[node];
    int e = start[node + 1];
    int k = s;
    for (; k + 2 <= e; k += 2) {
        int sn0 = csr_src[k];
        int sn1 = csr_src[k + 1];
        bf16x8 v0 = h8[sn0 * 16 + c8];
        bf16x8 v1 = h8[sn1 * 16 + c8];
#pragma unroll
        for (int i = 0; i < 8; ++i) acc[i] += bf2f(v0[i]);
#pragma unroll
        for (int i = 0; i < 8; ++i) acc[i] += bf2f(v1[i]);
    }
    if (k < e) {
        int sn0 = csr_src[k];
        bf16x8 v0 = h8[sn0 * 16 + c8];
#pragma unroll
        for (int i = 0; i < 8; ++i) acc[i] += bf2f(v0[i]);
    }

    short pk[8];
#pragma unroll
    for (int i = 0; i < 8; ++i) pk[i] = f2bf(acc[i]);
    *(bf16x8*)&m_bf[node * D + c8 * 8] = *(bf16x8*)pk;
}

// ---------------- MFMA MLP ----------------
// Block: 128 nodes x 128 features, 256 threads = 4 waves.
// Y^T = mfma(Wt_frag, m_frag). FINAL: out = m @ W + b (f32 out).
// Non-final: out bf16.
template <bool FINAL>
__global__ __launch_bounds__(256, 2) void mlp_mfma_kernel(
    const short* __restrict__ m_bf,
    const short* __restrict__ W1t,
    const float* __restrict__ b1,
    const float* __restrict__ gamma, const float* __restrict__ beta,
    const float* __restrict__ mean, const float* __restrict__ var,
    const short* __restrict__ W2t,
    const float* __restrict__ b2,
    const float* __restrict__ gproj, const int* __restrict__ batch,
    float* __restrict__ outf, short* __restrict__ outb) {
    __shared__ short sy[128 * 128];  // 32KB, XOR-swizzled rows
    __shared__ float sB1[128], sSc[128], sSb[128], sB2[128];

    const int tid = threadIdx.x;
    const int wid = tid >> 6;
    const int lane = tid & 63;
    const int lr = lane & 15;
    const int lk = lane >> 4;

    if (tid < 128) {
        sB1[tid] = b1[tid];
        if (!FINAL) {
            float sc = gamma[tid] * rsqrtf(var[tid] + BN_EPS);
            sSc[tid] = sc;
            sSb[tid] = beta[tid] - mean[tid] * sc;
            sB2[tid] = b2[tid];
        }
    }
    __syncthreads();

    const int nodeBase = blockIdx.x * 128 + (wid & 1) * 64;
    const int featBase = (wid >> 1) * 64;
    const int nlBase = (wid & 1) * 64;

    int nIdx[4];
#pragma unroll
    for (int mt = 0; mt < 4; ++mt) {
        int n = nodeBase + mt * 16 + lr;
        nIdx[mt] = (n < N_NODES) ? n : (N_NODES - 1);
    }

    bf16x8 wf[4][4];
#pragma unroll
    for (int ft = 0; ft < 4; ++ft)
#pragma unroll
        for (int kt = 0; kt < 4; ++kt)
            wf[ft][kt] = *(const bf16x8*)&W1t[(featBase + ft * 16 + lr) * D + kt * 32 + lk * 8];

    f32x4 acc[4][4];
#pragma unroll
    for (int ft = 0; ft < 4; ++ft)
#pragma unroll
        for (int mt = 0; mt < 4; ++mt)
            acc[ft][mt] = (f32x4)(0.0f);

#pragma unroll
    for (int kt = 0; kt < 4; ++kt) {
        bf16x8 mf[4];
#pragma unroll
        for (int mt = 0; mt < 4; ++mt)
            mf[mt] = *(const bf16x8*)&m_bf[nIdx[mt] * D + kt * 32 + lk * 8];
#pragma unroll
        for (int ft = 0; ft < 4; ++ft)
#pragma unroll
            for (int mt = 0; mt < 4; ++mt)
                acc[ft][mt] = __builtin_amdgcn_mfma_f32_16x16x32_bf16(wf[ft][kt], mf[mt],
                                                                      acc[ft][mt], 0, 0, 0);
    }

    if (FINAL) {
#pragma unroll
        for (int mt = 0; mt < 4; ++mt) {
            int node = nodeBase + mt * 16 + lr;
            if (node < N_NODES) {
#pragma unroll
                for (int ft = 0; ft < 4; ++ft) {
                    int f0 = featBase + ft * 16 + lk * 4;
                    float4 o;
                    o.x = acc[ft][mt][0] + sB1[f0 + 0];
                    o.y = acc[ft][mt][1] + sB1[f0 + 1];
                    o.z = acc[ft][mt][2] + sB1[f0 + 2];
                    o.w = acc[ft][mt][3] + sB1[f0 + 3];
                    *(float4*)&outf[node * D + f0] = o;
                }
            }
        }
        return;
    }

    // bias + LeakyReLU + BN -> bf16 -> LDS (swizzled)
#pragma unroll
    for (int ft = 0; ft < 4; ++ft) {
        int f0 = featBase + ft * 16 + lk * 4;
#pragma unroll
        for (int mt = 0; mt < 4; ++mt) {
            int nl = nlBase + mt * 16 + lr;
            short4 pk;
#pragma unroll
            for (int r = 0; r < 4; ++r) {
                float v = acc[ft][mt][r] + sB1[f0 + r];
                v = (v > 0.f) ? v : NEG_SLOPE * v;
                v = v * sSc[f0 + r] + sSb[f0 + r];
                ((short*)&pk)[r] = f2bf(v);
            }
            int byteoff = nl * 256 + f0 * 2;
            byteoff ^= (nl & 7) << 4;
            *(short4*)((char*)sy + byteoff) = pk;
        }
    }
    __syncthreads();

#pragma unroll
    for (int ft = 0; ft < 4; ++ft)
#pragma unroll
        for (int kt = 0; kt < 4; ++kt)
            wf[ft][kt] = *(const bf16x8*)&W2t[(featBase + ft * 16 + lr) * D + kt * 32 + lk * 8];

#pragma unroll
    for (int ft = 0; ft < 4; ++ft)
#pragma unroll
        for (int mt = 0; mt < 4; ++mt)
            acc[ft][mt] = (f32x4)(0.0f);

#pragma unroll
    for (int kt = 0; kt < 4; ++kt) {
        bf16x8 yf[4];
#pragma unroll
        for (int mt = 0; mt < 4; ++mt) {
            int nl = nlBase + mt * 16 + lr;
            int byteoff = nl * 256 + kt * 64 + lk * 16;
            byteoff ^= (nl & 7) << 4;
            yf[mt] = *(const bf16x8*)((char*)sy + byteoff);
        }
#pragma unroll
        for (int ft = 0; ft < 4; ++ft)
#pragma unroll
            for (int mt = 0; mt < 4; ++mt)
                acc[ft][mt] = __builtin_amdgcn_mfma_f32_16x16x32_bf16(wf[ft][kt], yf[mt],
                                                                      acc[ft][mt], 0, 0, 0);
    }

    // bias + LeakyReLU + gproj add -> bf16 store
#pragma unroll
    for (int mt = 0; mt < 4; ++mt) {
        int node = nodeBase + mt * 16 + lr;
        if (node >= N_NODES) continue;
        int bid = batch[node];
#pragma unroll
        for (int ft = 0; ft < 4; ++ft) {
            int f0 = featBase + ft * 16 + lk * 4;
            const float4 gp = *(const float4*)&gproj[bid * D + f0];
            float v0 = acc[ft][mt][0] + sB2[f0 + 0]; v0 = (v0 > 0.f) ? v0 : NEG_SLOPE * v0; v0 += gp.x;
            float v1 = acc[ft][mt][1] + sB2[f0 + 1]; v1 = (v1 > 0.f) ? v1 : NEG_SLOPE * v1; v1 += gp.y;
            float v2 = acc[ft][mt][2] + sB2[f0 + 2]; v2 = (v2 > 0.f) ? v2 : NEG_SLOPE * v2; v2 += gp.z;
            float v3 = acc[ft][mt][3] + sB2[f0 + 3]; v3 = (v3 > 0.f) ? v3 : NEG_SLOPE * v3; v3 += gp.w;
            short4 pk;
            pk.x = f2bf(v0); pk.y = f2bf(v1); pk.z = f2bf(v2); pk.w = f2bf(v3);
            *(short4*)&outb[node * D + f0] = pk;
        }
    }
}

// ---------------- launch ----------------

extern "C" void kernel_launch(void* const* d_in, const int* in_sizes, int n_in,
                              void* d_out, int out_size, void* d_ws, size_t ws_size,
                              hipStream_t stream) {
    const float* x = (const float*)d_in[0];
    const int* ei = (const int*)d_in[1];
    const int* src = ei;
    const int* dst = ei + N_EDGES;
    const int* batch = (const int*)d_in[2];
    const float* gs = (const float*)d_in[3];
    const float* W1s = (const float*)d_in[4];
    const float* b1s = (const float*)d_in[5];
    const float* gammas = (const float*)d_in[6];
    const float* betas = (const float*)d_in[7];
    const float* means = (const float*)d_in[8];
    const float* vars = (const float*)d_in[9];
    const float* W2s = (const float*)d_in[10];
    const float* b2s = (const float*)d_in[11];
    const float* statWs = (const float*)d_in[12];
    const float* statBs = (const float*)d_in[13];
    const float* fcW = (const float*)d_in[14];
    const float* fcB = (const float*)d_in[15];
    float* out = (float*)d_out;

    char* ws = (char*)d_ws;
    auto alloc = [&](size_t bytes) {
        char* p = ws;
        ws += (bytes + 255) / 256 * 256;
        return p;
    };
    int* deg = (int*)alloc(N_NODES * sizeof(int));
    int* incl = (int*)alloc(N_NODES * sizeof(int));
    int* bsum = (int*)alloc(64 * sizeof(int));
    int* start = (int*)alloc((N_NODES + 1) * sizeof(int));
    int* cursor = (int*)alloc(N_NODES * sizeof(int));
    int* csr_src = (int*)alloc(N_EDGES * sizeof(int));
    float* gproj = (float*)alloc((size_t)L_LAYERS * B_GRAPHS * D * sizeof(float));
    short* wt = (short*)alloc((size_t)7 * D * D * sizeof(short));
    short* xb = (short*)alloc((size_t)N_NODES * D * sizeof(short));
    short* hb = (short*)alloc((size_t)N_NODES * D * sizeof(short));
    short* m_bf = (short*)alloc((size_t)N_NODES * D * sizeof(short));

    const int nscan = (N_NODES + 2047) / 2048;

    zero_kernel<<<(N_NODES + 255) / 256, 256, 0, stream>>>(deg);
    count_kernel<<<(N_EDGES + 255) / 256, 256, 0, stream>>>(dst, deg);
    scan1_kernel<<<nscan, 256, 0, stream>>>(deg, incl, bsum);
    scan2_kernel<<<1, 64, 0, stream>>>(bsum, nscan);
    scan3_kernel<<<(N_NODES + 255) / 256, 256, 0, stream>>>(deg, incl, bsum, start, cursor);
    scatter_kernel<<<(N_EDGES + 255) / 256, 256, 0, stream>>>(src, dst, cursor, csr_src);

    gproj_kernel<<<dim3(B_GRAPHS, L_LAYERS), D, 0, stream>>>(gs, statWs, statBs, gproj);
    wconv_kernel<<<dim3(64, 7), 256, 0, stream>>>(W1s, W2s, fcW, wt);
    xconv_kernel<<<(N_NODES * D / 8 + 255) / 256, 256, 0, stream>>>(x, xb);

    const int agg_blocks = N_NODES / 16;  // 6250, exact
    const int mlp_blocks = (N_NODES + 127) / 128;

    // layer 0
    agg_kernel<<<agg_blocks, 256, 0, stream>>>(xb, start, csr_src, m_bf);
    mlp_mfma_kernel<false><<<mlp_blocks, 256, 0, stream>>>(
        m_bf, wt + 0 * D * D, b1s + 0 * D, gammas + 0 * D, betas + 0 * D, means + 0 * D,
        vars + 0 * D, wt + 3 * D * D, b2s + 0 * D, gproj + 0 * B_GRAPHS * D, batch, nullptr, hb);
    // layer 1
    agg_kernel<<<agg_blocks, 256, 0, stream>>>(hb, start, csr_src, m_bf);
    mlp_mfma_kernel<false><<<mlp_blocks, 256, 0, stream>>>(
        m_bf, wt + 1 * D * D, b1s + 1 * D, gammas + 1 * D, betas + 1 * D, means + 1 * D,
        vars + 1 * D, wt + 4 * D * D, b2s + 1 * D, gproj + 1 * B_GRAPHS * D, batch, nullptr, hb);
    // layer 2
    agg_kernel<<<agg_blocks, 256, 0, stream>>>(hb, start, csr_src, m_bf);
    mlp_mfma_kernel<false><<<mlp_blocks, 256, 0, stream>>>(
        m_bf, wt + 2 * D * D, b1s + 2 * D, gammas + 2 * D, betas + 2 * D, means + 2 * D,
        vars + 2 * D, wt + 5 * D * D, b2s + 2 * D, gproj + 2 * B_GRAPHS * D, batch, nullptr, hb);
    // fc_out
    mlp_mfma_kernel<true><<<mlp_blocks, 256, 0, stream>>>(
        hb, wt + 6 * D * D, fcB, nullptr, nullptr, nullptr, nullptr, nullptr, nullptr, nullptr,
        batch, out, nullptr);
}

// Round 4
// 424.539 us; speedup vs baseline: 2.4275x; 1.2721x over previous
//
#include <hip/hip_runtime.h>
#include <math.h>

#define N_NODES 100000
#define N_EDGES 1600000
#define D 128
#define L_LAYERS 3
#define P_STATS 7
#define B_GRAPHS 64
#define BN_EPS 1e-5f
#define NEG_SLOPE 0.2f

#define NB 196        // buckets of 512 dst nodes: 100000 >> 9 -> 0..195
#define BCAP 10240    // per-bucket capacity (mean 8192, std ~90)
#define EPB 6400      // edges per bucketA block -> 250 blocks

typedef __attribute__((ext_vector_type(8))) short bf16x8;
typedef __attribute__((ext_vector_type(4))) float f32x4;

static __device__ __forceinline__ short f2bf(float f) {
    union { float f; unsigned u; } v;
    v.f = f;
    unsigned r = v.u + 0x7fffu + ((v.u >> 16) & 1u);  // RNE
    return (short)(r >> 16);
}

static __device__ __forceinline__ float bf2f(short s) {
    union { unsigned u; float f; } v;
    v.u = ((unsigned)(unsigned short)s) << 16;
    return v.f;
}

// ---------------- CSR build (bucketed) ----------------

__global__ void zero_n_kernel(int* __restrict__ p, int n) {
    int i = blockIdx.x * blockDim.x + threadIdx.x;
    if (i < n) p[i] = 0;
}

// Pass A: partition edges into NB append-buffers of (src,dst) pairs.
__global__ __launch_bounds__(256) void bucketA_kernel(const int* __restrict__ src,
                                                      const int* __restrict__ dst,
                                                      int* __restrict__ bucket_cnt,
                                                      int2* __restrict__ bucketbuf) {
    __shared__ int s_src[EPB];
    __shared__ int s_dst[EPB];
    __shared__ int hist[NB], base[NB], loc[NB];
    const int tid = threadIdx.x;
    const int e0 = blockIdx.x * EPB;
    for (int i = tid; i < NB; i += 256) { hist[i] = 0; loc[i] = 0; }
    __syncthreads();
    for (int i = tid; i < EPB; i += 256) {
        int s = src[e0 + i];
        int d = dst[e0 + i];
        s_src[i] = s;
        s_dst[i] = d;
        atomicAdd(&hist[d >> 9], 1);
    }
    __syncthreads();
    for (int i = tid; i < NB; i += 256)
        base[i] = hist[i] ? atomicAdd(&bucket_cnt[i], hist[i]) : 0;
    __syncthreads();
    for (int i = tid; i < EPB; i += 256) {
        int d = s_dst[i];
        int b = d >> 9;
        int off = atomicAdd(&loc[b], 1);
        int idx = base[b] + off;
        if (idx < BCAP) bucketbuf[(size_t)b * BCAP + idx] = make_int2(s_src[i], d);
    }
}

// Pass B1: per-bucket degree histogram -> deg (coalesced write).
__global__ __launch_bounds__(256) void bucketB1_kernel(const int* __restrict__ bucket_cnt,
                                                       const int2* __restrict__ bucketbuf,
                                                       int* __restrict__ deg) {
    __shared__ int hist[512];
    const int b = blockIdx.x;
    for (int i = threadIdx.x; i < 512; i += 256) hist[i] = 0;
    __syncthreads();
    int cnt = min(bucket_cnt[b], BCAP);
    for (int i = threadIdx.x; i < cnt; i += 256) {
        int d = bucketbuf[(size_t)b * BCAP + i].y;
        atomicAdd(&hist[d & 511], 1);
    }
    __syncthreads();
    int nbase = b << 9;
    for (int i = threadIdx.x; i < 512; i += 256) {
        int node = nbase + i;
        if (node < N_NODES) deg[node] = hist[i];
    }
}

// Pass B2: per-bucket final scatter; positions land in a ~32KB L2-resident window.
__global__ __launch_bounds__(256) void bucketB2_kernel(const int* __restrict__ bucket_cnt,
                                                       const int2* __restrict__ bucketbuf,
                                                       int* __restrict__ cursor,
                                                       int* __restrict__ csr_src) {
    const int b = blockIdx.x;
    int cnt = min(bucket_cnt[b], BCAP);
    for (int i = threadIdx.x; i < cnt; i += 256) {
        int2 p = bucketbuf[(size_t)b * BCAP + i];
        int pos = atomicAdd(&cursor[p.y], 1);
        csr_src[pos] = p.x;
    }
}

// ---------------- scans (unchanged) ----------------

__global__ void scan1_kernel(const int* __restrict__ deg, int* __restrict__ incl,
                             int* __restrict__ bsum) {
    __shared__ int s[256];
    const int tid = threadIdx.x;
    const int base = blockIdx.x * 2048;
    int v[8];
    int sum = 0;
    const int idx0 = base + tid * 8;
#pragma unroll
    for (int i = 0; i < 8; ++i) {
        int idx = idx0 + i;
        int d = (idx < N_NODES) ? deg[idx] : 0;
        sum += d;
        v[i] = sum;
    }
    s[tid] = sum;
    __syncthreads();
    for (int off = 1; off < 256; off <<= 1) {
        int t = (tid >= off) ? s[tid - off] : 0;
        __syncthreads();
        s[tid] += t;
        __syncthreads();
    }
    int prev = (tid > 0) ? s[tid - 1] : 0;
#pragma unroll
    for (int i = 0; i < 8; ++i) {
        int idx = idx0 + i;
        if (idx < N_NODES) incl[idx] = v[i] + prev;
    }
    if (tid == 255) bsum[blockIdx.x] = s[255];
}

__global__ void scan2_kernel(int* __restrict__ bsum, int nb) {
    if (threadIdx.x == 0 && blockIdx.x == 0) {
        int run = 0;
        for (int i = 0; i < nb; ++i) { int t = bsum[i]; bsum[i] = run; run += t; }
    }
}

__global__ void scan3_kernel(const int* __restrict__ deg, const int* __restrict__ incl,
                             const int* __restrict__ bsum, int* __restrict__ start,
                             int* __restrict__ cursor) {
    int i = blockIdx.x * blockDim.x + threadIdx.x;
    if (i < N_NODES) {
        int inc = incl[i] + bsum[i >> 11];
        int st = inc - deg[i];
        start[i] = st;
        cursor[i] = st;
    }
    if (i == 0) start[N_NODES] = N_EDGES;
}

// ---------------- per-graph stat projections ----------------
__global__ void gproj_kernel(const float* __restrict__ gs, const float* __restrict__ statWs,
                             const float* __restrict__ statBs, float* __restrict__ gproj) {
    int b = blockIdx.x;
    int l = blockIdx.y;
    int j = threadIdx.x;
    float acc = statBs[l * D + j];
#pragma unroll
    for (int p = 0; p < P_STATS; ++p) {
        float g = gs[b * P_STATS + p];
        if (g != g) g = -100.0f;
        acc += g * statWs[(l * P_STATS + p) * D + j];
    }
    gproj[(l * B_GRAPHS + b) * D + j] = acc;
}

// ---------------- weight convert: W[k][n] f32 -> Wt[n][k] bf16 ----------------
__global__ void wconv_kernel(const float* __restrict__ W1s, const float* __restrict__ W2s,
                             const float* __restrict__ fcW, short* __restrict__ wt) {
    int mid = blockIdx.y;
    const float* src = (mid < 3) ? (W1s + mid * D * D)
                                 : ((mid < 6) ? (W2s + (mid - 3) * D * D) : fcW);
    short* dstm = wt + mid * D * D;
    int i = blockIdx.x * 256 + threadIdx.x;
    int k = i >> 7, n = i & 127;
    dstm[n * D + k] = f2bf(src[i]);
}

// ---------------- x f32 -> bf16 ----------------
__global__ __launch_bounds__(256) void xconv_kernel(const float* __restrict__ x,
                                                    short* __restrict__ xb) {
    int i = blockIdx.x * 256 + threadIdx.x;
    const float4* x4 = (const float4*)x;
    float4 a = x4[i * 2], b = x4[i * 2 + 1];
    short s[8];
    s[0] = f2bf(a.x); s[1] = f2bf(a.y); s[2] = f2bf(a.z); s[3] = f2bf(a.w);
    s[4] = f2bf(b.x); s[5] = f2bf(b.y); s[6] = f2bf(b.z); s[7] = f2bf(b.w);
    *(bf16x8*)&xb[i * 8] = *(bf16x8*)s;
}

// ---------------- aggregation: m = h + segment_sum(h[src], dst), bf16 in/out ----------------
__global__ __launch_bounds__(256) void agg_kernel(const short* __restrict__ hb,
                                                  const int* __restrict__ start,
                                                  const int* __restrict__ csr_src,
                                                  short* __restrict__ m_bf) {
    int node = blockIdx.x * 16 + (threadIdx.x >> 4);
    int c8 = threadIdx.x & 15;
    const bf16x8* h8 = (const bf16x8*)hb;

    bf16x8 own = h8[node * 16 + c8];
    float acc[8];
#pragma unroll
    for (int i = 0; i < 8; ++i) acc[i] = bf2f(own[i]);

    int s = start[node];
    int e = start[node + 1];
    int k = s;
    for (; k + 2 <= e; k += 2) {
        int sn0 = csr_src[k];
        int sn1 = csr_src[k + 1];
        bf16x8 v0 = h8[sn0 * 16 + c8];
        bf16x8 v1 = h8[sn1 * 16 + c8];
#pragma unroll
        for (int i = 0; i < 8; ++i) acc[i] += bf2f(v0[i]);
#pragma unroll
        for (int i = 0; i < 8; ++i) acc[i] += bf2f(v1[i]);
    }
    if (k < e) {
        int sn0 = csr_src[k];
        bf16x8 v0 = h8[sn0 * 16 + c8];
#pragma unroll
        for (int i = 0; i < 8; ++i) acc[i] += bf2f(v0[i]);
    }

    short pk[8];
#pragma unroll
    for (int i = 0; i < 8; ++i) pk[i] = f2bf(acc[i]);
    *(bf16x8*)&m_bf[node * D + c8 * 8] = *(bf16x8*)pk;
}

// ---------------- MFMA MLP ----------------
template <bool FINAL>
__global__ __launch_bounds__(256, 2) void mlp_mfma_kernel(
    const short* __restrict__ m_bf,
    const short* __restrict__ W1t,
    const float* __restrict__ b1,
    const float* __restrict__ gamma, const float* __restrict__ beta,
    const float* __restrict__ mean, const float* __restrict__ var,
    const short* __restrict__ W2t,
    const float* __restrict__ b2,
    const float* __restrict__ gproj, const int* __restrict__ batch,
    float* __restrict__ outf, short* __restrict__ outb) {
    __shared__ short sy[128 * 128];
    __shared__ float sB1[128], sSc[128], sSb[128], sB2[128];

    const int tid = threadIdx.x;
    const int wid = tid >> 6;
    const int lane = tid & 63;
    const int lr = lane & 15;
    const int lk = lane >> 4;

    if (tid < 128) {
        sB1[tid] = b1[tid];
        if (!FINAL) {
            float sc = gamma[tid] * rsqrtf(var[tid] + BN_EPS);
            sSc[tid] = sc;
            sSb[tid] = beta[tid] - mean[tid] * sc;
            sB2[tid] = b2[tid];
        }
    }
    __syncthreads();

    const int nodeBase = blockIdx.x * 128 + (wid & 1) * 64;
    const int featBase = (wid >> 1) * 64;
    const int nlBase = (wid & 1) * 64;

    int nIdx[4];
#pragma unroll
    for (int mt = 0; mt < 4; ++mt) {
        int n = nodeBase + mt * 16 + lr;
        nIdx[mt] = (n < N_NODES) ? n : (N_NODES - 1);
    }

    bf16x8 wf[4][4];
#pragma unroll
    for (int ft = 0; ft < 4; ++ft)
#pragma unroll
        for (int kt = 0; kt < 4; ++kt)
            wf[ft][kt] = *(const bf16x8*)&W1t[(featBase + ft * 16 + lr) * D + kt * 32 + lk * 8];

    f32x4 acc[4][4];
#pragma unroll
    for (int ft = 0; ft < 4; ++ft)
#pragma unroll
        for (int mt = 0; mt < 4; ++mt)
            acc[ft][mt] = (f32x4)(0.0f);

#pragma unroll
    for (int kt = 0; kt < 4; ++kt) {
        bf16x8 mf[4];
#pragma unroll
        for (int mt = 0; mt < 4; ++mt)
            mf[mt] = *(const bf16x8*)&m_bf[nIdx[mt] * D + kt * 32 + lk * 8];
#pragma unroll
        for (int ft = 0; ft < 4; ++ft)
#pragma unroll
            for (int mt = 0; mt < 4; ++mt)
                acc[ft][mt] = __builtin_amdgcn_mfma_f32_16x16x32_bf16(wf[ft][kt], mf[mt],
                                                                      acc[ft][mt], 0, 0, 0);
    }

    if (FINAL) {
#pragma unroll
        for (int mt = 0; mt < 4; ++mt) {
            int node = nodeBase + mt * 16 + lr;
            if (node < N_NODES) {
#pragma unroll
                for (int ft = 0; ft < 4; ++ft) {
                    int f0 = featBase + ft * 16 + lk * 4;
                    float4 o;
                    o.x = acc[ft][mt][0] + sB1[f0 + 0];
                    o.y = acc[ft][mt][1] + sB1[f0 + 1];
                    o.z = acc[ft][mt][2] + sB1[f0 + 2];
                    o.w = acc[ft][mt][3] + sB1[f0 + 3];
                    *(float4*)&outf[node * D + f0] = o;
                }
            }
        }
        return;
    }

#pragma unroll
    for (int ft = 0; ft < 4; ++ft) {
        int f0 = featBase + ft * 16 + lk * 4;
#pragma unroll
        for (int mt = 0; mt < 4; ++mt) {
            int nl = nlBase + mt * 16 + lr;
            short4 pk;
#pragma unroll
            for (int r = 0; r < 4; ++r) {
                float v = acc[ft][mt][r] + sB1[f0 + r];
                v = (v > 0.f) ? v : NEG_SLOPE * v;
                v = v * sSc[f0 + r] + sSb[f0 + r];
                ((short*)&pk)[r] = f2bf(v);
            }
            int byteoff = nl * 256 + f0 * 2;
            byteoff ^= (nl & 7) << 4;
            *(short4*)((char*)sy + byteoff) = pk;
        }
    }
    __syncthreads();

#pragma unroll
    for (int ft = 0; ft < 4; ++ft)
#pragma unroll
        for (int kt = 0; kt < 4; ++kt)
            wf[ft][kt] = *(const bf16x8*)&W2t[(featBase + ft * 16 + lr) * D + kt * 32 + lk * 8];

#pragma unroll
    for (int ft = 0; ft < 4; ++ft)
#pragma unroll
        for (int mt = 0; mt < 4; ++mt)
            acc[ft][mt] = (f32x4)(0.0f);

#pragma unroll
    for (int kt = 0; kt < 4; ++kt) {
        bf16x8 yf[4];
#pragma unroll
        for (int mt = 0; mt < 4; ++mt) {
            int nl = nlBase + mt * 16 + lr;
            int byteoff = nl * 256 + kt * 64 + lk * 16;
            byteoff ^= (nl & 7) << 4;
            yf[mt] = *(const bf16x8*)((char*)sy + byteoff);
        }
#pragma unroll
        for (int ft = 0; ft < 4; ++ft)
#pragma unroll
            for (int mt = 0; mt < 4; ++mt)
                acc[ft][mt] = __builtin_amdgcn_mfma_f32_16x16x32_bf16(wf[ft][kt], yf[mt],
                                                                      acc[ft][mt], 0, 0, 0);
    }

#pragma unroll
    for (int mt = 0; mt < 4; ++mt) {
        int node = nodeBase + mt * 16 + lr;
        if (node >= N_NODES) continue;
        int bid = batch[node];
#pragma unroll
        for (int ft = 0; ft < 4; ++ft) {
            int f0 = featBase + ft * 16 + lk * 4;
            const float4 gp = *(const float4*)&gproj[bid * D + f0];
            float v0 = acc[ft][mt][0] + sB2[f0 + 0]; v0 = (v0 > 0.f) ? v0 : NEG_SLOPE * v0; v0 += gp.x;
            float v1 = acc[ft][mt][1] + sB2[f0 + 1]; v1 = (v1 > 0.f) ? v1 : NEG_SLOPE * v1; v1 += gp.y;
            float v2 = acc[ft][mt][2] + sB2[f0 + 2]; v2 = (v2 > 0.f) ? v2 : NEG_SLOPE * v2; v2 += gp.z;
            float v3 = acc[ft][mt][3] + sB2[f0 + 3]; v3 = (v3 > 0.f) ? v3 : NEG_SLOPE * v3; v3 += gp.w;
            short4 pk;
            pk.x = f2bf(v0); pk.y = f2bf(v1); pk.z = f2bf(v2); pk.w = f2bf(v3);
            *(short4*)&outb[node * D + f0] = pk;
        }
    }
}

// ---------------- launch ----------------

extern "C" void kernel_launch(void* const* d_in, const int* in_sizes, int n_in,
                              void* d_out, int out_size, void* d_ws, size_t ws_size,
                              hipStream_t stream) {
    const float* x = (const float*)d_in[0];
    const int* ei = (const int*)d_in[1];
    const int* src = ei;
    const int* dst = ei + N_EDGES;
    const int* batch = (const int*)d_in[2];
    const float* gs = (const float*)d_in[3];
    const float* W1s = (const float*)d_in[4];
    const float* b1s = (const float*)d_in[5];
    const float* gammas = (const float*)d_in[6];
    const float* betas = (const float*)d_in[7];
    const float* means = (const float*)d_in[8];
    const float* vars = (const float*)d_in[9];
    const float* W2s = (const float*)d_in[10];
    const float* b2s = (const float*)d_in[11];
    const float* statWs = (const float*)d_in[12];
    const float* statBs = (const float*)d_in[13];
    const float* fcW = (const float*)d_in[14];
    const float* fcB = (const float*)d_in[15];
    float* out = (float*)d_out;

    char* ws = (char*)d_ws;
    auto alloc = [&](size_t bytes) {
        char* p = ws;
        ws += (bytes + 255) / 256 * 256;
        return p;
    };
    int* deg = (int*)alloc(N_NODES * sizeof(int));
    int* incl = (int*)alloc(N_NODES * sizeof(int));
    int* bsum = (int*)alloc(64 * sizeof(int));
    int* start = (int*)alloc((N_NODES + 1) * sizeof(int));
    int* cursor = (int*)alloc(N_NODES * sizeof(int));
    int* csr_src = (int*)alloc(N_EDGES * sizeof(int));
    int* bucket_cnt = (int*)alloc(NB * sizeof(int));
    int2* bucketbuf = (int2*)alloc((size_t)NB * BCAP * sizeof(int2));
    float* gproj = (float*)alloc((size_t)L_LAYERS * B_GRAPHS * D * sizeof(float));
    short* wt = (short*)alloc((size_t)7 * D * D * sizeof(short));
    short* xb = (short*)alloc((size_t)N_NODES * D * sizeof(short));
    short* hb = (short*)alloc((size_t)N_NODES * D * sizeof(short));
    short* m_bf = (short*)alloc((size_t)N_NODES * D * sizeof(short));

    const int nscan = (N_NODES + 2047) / 2048;

    // CSR build, bucketed
    zero_n_kernel<<<1, 256, 0, stream>>>(bucket_cnt, NB);
    bucketA_kernel<<<N_EDGES / EPB, 256, 0, stream>>>(src, dst, bucket_cnt, bucketbuf);
    bucketB1_kernel<<<NB, 256, 0, stream>>>(bucket_cnt, bucketbuf, deg);
    scan1_kernel<<<nscan, 256, 0, stream>>>(deg, incl, bsum);
    scan2_kernel<<<1, 64, 0, stream>>>(bsum, nscan);
    scan3_kernel<<<(N_NODES + 255) / 256, 256, 0, stream>>>(deg, incl, bsum, start, cursor);
    bucketB2_kernel<<<NB, 256, 0, stream>>>(bucket_cnt, bucketbuf, cursor, csr_src);

    gproj_kernel<<<dim3(B_GRAPHS, L_LAYERS), D, 0, stream>>>(gs, statWs, statBs, gproj);
    wconv_kernel<<<dim3(64, 7), 256, 0, stream>>>(W1s, W2s, fcW, wt);
    xconv_kernel<<<(N_NODES * D / 8 + 255) / 256, 256, 0, stream>>>(x, xb);

    const int agg_blocks = N_NODES / 16;
    const int mlp_blocks = (N_NODES + 127) / 128;

    // layer 0
    agg_kernel<<<agg_blocks, 256, 0, stream>>>(xb, start, csr_src, m_bf);
    mlp_mfma_kernel<false><<<mlp_blocks, 256, 0, stream>>>(
        m_bf, wt + 0 * D * D, b1s + 0 * D, gammas + 0 * D, betas + 0 * D, means + 0 * D,
        vars + 0 * D, wt + 3 * D * D, b2s + 0 * D, gproj + 0 * B_GRAPHS * D, batch, nullptr, hb);
    // layer 1
    agg_kernel<<<agg_blocks, 256, 0, stream>>>(hb, start, csr_src, m_bf);
    mlp_mfma_kernel<false><<<mlp_blocks, 256, 0, stream>>>(
        m_bf, wt + 1 * D * D, b1s + 1 * D, gammas + 1 * D, betas + 1 * D, means + 1 * D,
        vars + 1 * D, wt + 4 * D * D, b2s + 1 * D, gproj + 1 * B_GRAPHS * D, batch, nullptr, hb);
    // layer 2
    agg_kernel<<<agg_blocks, 256, 0, stream>>>(hb, start, csr_src, m_bf);
    mlp_mfma_kernel<false><<<mlp_blocks, 256, 0, stream>>>(
        m_bf, wt + 2 * D * D, b1s + 2 * D, gammas + 2 * D, betas + 2 * D, means + 2 * D,
        vars + 2 * D, wt + 5 * D * D, b2s + 2 * D, gproj + 2 * B_GRAPHS * D, batch, nullptr, hb);
    // fc_out
    mlp_mfma_kernel<true><<<mlp_blocks, 256, 0, stream>>>(
        hb, wt + 6 * D * D, fcB, nullptr, nullptr, nullptr, nullptr, nullptr, nullptr, nullptr,
        batch, out, nullptr);
}

// Round 5
// 394.061 us; speedup vs baseline: 2.6153x; 1.0773x over previous
//
#include <hip/hip_runtime.h>
#include <math.h>

#define N_NODES 100000
#define N_EDGES 1600000
#define D 128
#define L_LAYERS 3
#define P_STATS 7
#define B_GRAPHS 64
#define BN_EPS 1e-5f
#define NEG_SLOPE 0.2f

#define NB 196        // buckets of 512 dst nodes
#define BCAP 10240
#define EPB 6400

typedef __attribute__((ext_vector_type(8))) short bf16x8;
typedef __attribute__((ext_vector_type(4))) float f32x4;

static __device__ __forceinline__ short f2bf(float f) {
    union { float f; unsigned u; } v;
    v.f = f;
    unsigned r = v.u + 0x7fffu + ((v.u >> 16) & 1u);  // RNE
    return (short)(r >> 16);
}

static __device__ __forceinline__ float bf2f(short s) {
    union { unsigned u; float f; } v;
    v.u = ((unsigned)(unsigned short)s) << 16;
    return v.f;
}

// ---------------- CSR build (bucketed) ----------------

__global__ void zero_n_kernel(int* __restrict__ p, int n) {
    int i = blockIdx.x * blockDim.x + threadIdx.x;
    if (i < n) p[i] = 0;
}

__global__ __launch_bounds__(256) void bucketA_kernel(const int* __restrict__ src,
                                                      const int* __restrict__ dst,
                                                      int* __restrict__ bucket_cnt,
                                                      int2* __restrict__ bucketbuf) {
    __shared__ int s_src[EPB];
    __shared__ int s_dst[EPB];
    __shared__ int hist[NB], base[NB], loc[NB];
    const int tid = threadIdx.x;
    const int e0 = blockIdx.x * EPB;
    for (int i = tid; i < NB; i += 256) { hist[i] = 0; loc[i] = 0; }
    __syncthreads();
    for (int i = tid; i < EPB; i += 256) {
        int s = src[e0 + i];
        int d = dst[e0 + i];
        s_src[i] = s;
        s_dst[i] = d;
        atomicAdd(&hist[d >> 9], 1);
    }
    __syncthreads();
    for (int i = tid; i < NB; i += 256)
        base[i] = hist[i] ? atomicAdd(&bucket_cnt[i], hist[i]) : 0;
    __syncthreads();
    for (int i = tid; i < EPB; i += 256) {
        int d = s_dst[i];
        int b = d >> 9;
        int off = atomicAdd(&loc[b], 1);
        int idx = base[b] + off;
        if (idx < BCAP) bucketbuf[(size_t)b * BCAP + idx] = make_int2(s_src[i], d);
    }
}

__global__ __launch_bounds__(256) void bucketB1_kernel(const int* __restrict__ bucket_cnt,
                                                       const int2* __restrict__ bucketbuf,
                                                       int* __restrict__ deg) {
    __shared__ int hist[512];
    const int b = blockIdx.x;
    for (int i = threadIdx.x; i < 512; i += 256) hist[i] = 0;
    __syncthreads();
    int cnt = min(bucket_cnt[b], BCAP);
    for (int i = threadIdx.x; i < cnt; i += 256) {
        int d = bucketbuf[(size_t)b * BCAP + i].y;
        atomicAdd(&hist[d & 511], 1);
    }
    __syncthreads();
    int nbase = b << 9;
    for (int i = threadIdx.x; i < 512; i += 256) {
        int node = nbase + i;
        if (node < N_NODES) deg[node] = hist[i];
    }
}

__global__ __launch_bounds__(256) void bucketB2_kernel(const int* __restrict__ bucket_cnt,
                                                       const int2* __restrict__ bucketbuf,
                                                       int* __restrict__ cursor,
                                                       int* __restrict__ csr_src) {
    const int b = blockIdx.x;
    int cnt = min(bucket_cnt[b], BCAP);
    for (int i = threadIdx.x; i < cnt; i += 256) {
        int2 p = bucketbuf[(size_t)b * BCAP + i];
        int pos = atomicAdd(&cursor[p.y], 1);
        csr_src[pos] = p.x;
    }
}

// ---------------- scans ----------------

__global__ void scan1_kernel(const int* __restrict__ deg, int* __restrict__ incl,
                             int* __restrict__ bsum) {
    __shared__ int s[256];
    const int tid = threadIdx.x;
    const int base = blockIdx.x * 2048;
    int v[8];
    int sum = 0;
    const int idx0 = base + tid * 8;
#pragma unroll
    for (int i = 0; i < 8; ++i) {
        int idx = idx0 + i;
        int d = (idx < N_NODES) ? deg[idx] : 0;
        sum += d;
        v[i] = sum;
    }
    s[tid] = sum;
    __syncthreads();
    for (int off = 1; off < 256; off <<= 1) {
        int t = (tid >= off) ? s[tid - off] : 0;
        __syncthreads();
        s[tid] += t;
        __syncthreads();
    }
    int prev = (tid > 0) ? s[tid - 1] : 0;
#pragma unroll
    for (int i = 0; i < 8; ++i) {
        int idx = idx0 + i;
        if (idx < N_NODES) incl[idx] = v[i] + prev;
    }
    if (tid == 255) bsum[blockIdx.x] = s[255];
}

__global__ void scan2_kernel(int* __restrict__ bsum, int nb) {
    if (threadIdx.x == 0 && blockIdx.x == 0) {
        int run = 0;
        for (int i = 0; i < nb; ++i) { int t = bsum[i]; bsum[i] = run; run += t; }
    }
}

__global__ void scan3_kernel(const int* __restrict__ deg, const int* __restrict__ incl,
                             const int* __restrict__ bsum, int* __restrict__ start,
                             int* __restrict__ cursor) {
    int i = blockIdx.x * blockDim.x + threadIdx.x;
    if (i < N_NODES) {
        int inc = incl[i] + bsum[i >> 11];
        int st = inc - deg[i];
        start[i] = st;
        cursor[i] = st;
    }
    if (i == 0) start[N_NODES] = N_EDGES;
}

// ---------------- per-graph stat projections ----------------
__global__ void gproj_kernel(const float* __restrict__ gs, const float* __restrict__ statWs,
                             const float* __restrict__ statBs, float* __restrict__ gproj) {
    int b = blockIdx.x;
    int l = blockIdx.y;
    int j = threadIdx.x;
    float acc = statBs[l * D + j];
#pragma unroll
    for (int p = 0; p < P_STATS; ++p) {
        float g = gs[b * P_STATS + p];
        if (g != g) g = -100.0f;
        acc += g * statWs[(l * P_STATS + p) * D + j];
    }
    gproj[(l * B_GRAPHS + b) * D + j] = acc;
}

// ---------------- weight convert: W[k][n] f32 -> Wt[n][k] bf16 ----------------
__global__ void wconv_kernel(const float* __restrict__ W1s, const float* __restrict__ W2s,
                             const float* __restrict__ fcW, short* __restrict__ wt) {
    int mid = blockIdx.y;
    const float* src = (mid < 3) ? (W1s + mid * D * D)
                                 : ((mid < 6) ? (W2s + (mid - 3) * D * D) : fcW);
    short* dstm = wt + mid * D * D;
    int i = blockIdx.x * 256 + threadIdx.x;
    int k = i >> 7, n = i & 127;
    dstm[n * D + k] = f2bf(src[i]);
}

// ---------------- x f32 -> bf16 ----------------
__global__ __launch_bounds__(256) void xconv_kernel(const float* __restrict__ x,
                                                    short* __restrict__ xb) {
    int i = blockIdx.x * 256 + threadIdx.x;
    const float4* x4 = (const float4*)x;
    float4 a = x4[i * 2], b = x4[i * 2 + 1];
    short s[8];
    s[0] = f2bf(a.x); s[1] = f2bf(a.y); s[2] = f2bf(a.z); s[3] = f2bf(a.w);
    s[4] = f2bf(b.x); s[5] = f2bf(b.y); s[6] = f2bf(b.z); s[7] = f2bf(b.w);
    *(bf16x8*)&xb[i * 8] = *(bf16x8*)s;
}

// ---------------- aggregation (unroll-4 for MLP) ----------------
__global__ __launch_bounds__(256) void agg_kernel(const short* __restrict__ hb,
                                                  const int* __restrict__ start,
                                                  const int* __restrict__ csr_src,
                                                  short* __restrict__ m_bf) {
    int node = blockIdx.x * 16 + (threadIdx.x >> 4);
    int c8 = threadIdx.x & 15;
    const bf16x8* h8 = (const bf16x8*)hb;

    bf16x8 own = h8[node * 16 + c8];
    float acc[8];
#pragma unroll
    for (int i = 0; i < 8; ++i) acc[i] = bf2f(own[i]);

    int s = start[node];
    int e = start[node + 1];
    int k = s;
    for (; k + 4 <= e; k += 4) {
        int sn0 = csr_src[k];
        int sn1 = csr_src[k + 1];
        int sn2 = csr_src[k + 2];
        int sn3 = csr_src[k + 3];
        bf16x8 v0 = h8[sn0 * 16 + c8];
        bf16x8 v1 = h8[sn1 * 16 + c8];
        bf16x8 v2 = h8[sn2 * 16 + c8];
        bf16x8 v3 = h8[sn3 * 16 + c8];
#pragma unroll
        for (int i = 0; i < 8; ++i) acc[i] += bf2f(v0[i]);
#pragma unroll
        for (int i = 0; i < 8; ++i) acc[i] += bf2f(v1[i]);
#pragma unroll
        for (int i = 0; i < 8; ++i) acc[i] += bf2f(v2[i]);
#pragma unroll
        for (int i = 0; i < 8; ++i) acc[i] += bf2f(v3[i]);
    }
    for (; k < e; ++k) {
        int sn0 = csr_src[k];
        bf16x8 v0 = h8[sn0 * 16 + c8];
#pragma unroll
        for (int i = 0; i < 8; ++i) acc[i] += bf2f(v0[i]);
    }

    short pk[8];
#pragma unroll
    for (int i = 0; i < 8; ++i) pk[i] = f2bf(acc[i]);
    *(bf16x8*)&m_bf[node * D + c8 * 8] = *(bf16x8*)pk;
}

// ---------------- MFMA MLP (optionally with fused fc_out) ----------------
// Block: 128 nodes x 128 features, 256 threads = 4 waves.
// FUSE_FC=false: write bf16 h to outb. FUSE_FC=true (layer 2): keep h in LDS,
// run GEMM3 with fcW, write f32 out.
template <bool FUSE_FC>
__global__ __launch_bounds__(256, FUSE_FC ? 2 : 4) void mlp_mfma_kernel(
    const short* __restrict__ m_bf,
    const short* __restrict__ W1t,
    const float* __restrict__ b1,
    const float* __restrict__ gamma, const float* __restrict__ beta,
    const float* __restrict__ mean, const float* __restrict__ var,
    const short* __restrict__ W2t,
    const float* __restrict__ b2,
    const float* __restrict__ gproj, const int* __restrict__ batch,
    const short* __restrict__ Wft, const float* __restrict__ fcb,
    float* __restrict__ outf, short* __restrict__ outb) {
    __shared__ short sy[128 * 128];  // 32KB, XOR-swizzled rows
    __shared__ float sB1[128], sSc[128], sSb[128], sB2[128], sFC[128];

    const int tid = threadIdx.x;
    const int wid = tid >> 6;
    const int lane = tid & 63;
    const int lr = lane & 15;
    const int lk = lane >> 4;

    if (tid < 128) {
        sB1[tid] = b1[tid];
        float sc = gamma[tid] * rsqrtf(var[tid] + BN_EPS);
        sSc[tid] = sc;
        sSb[tid] = beta[tid] - mean[tid] * sc;
        sB2[tid] = b2[tid];
        if (FUSE_FC) sFC[tid] = fcb[tid];
    }
    __syncthreads();

    const int nodeBase = blockIdx.x * 128 + (wid & 1) * 64;
    const int featBase = (wid >> 1) * 64;
    const int nlBase = (wid & 1) * 64;

    int nIdx[4];
#pragma unroll
    for (int mt = 0; mt < 4; ++mt) {
        int n = nodeBase + mt * 16 + lr;
        nIdx[mt] = (n < N_NODES) ? n : (N_NODES - 1);
    }

    f32x4 acc[4][4];
#pragma unroll
    for (int ft = 0; ft < 4; ++ft)
#pragma unroll
        for (int mt = 0; mt < 4; ++mt)
            acc[ft][mt] = (f32x4)(0.0f);

    // ---- GEMM1 (per-kt fragment loads to cap VGPR) ----
#pragma unroll
    for (int kt = 0; kt < 4; ++kt) {
        bf16x8 wfk[4];
#pragma unroll
        for (int ft = 0; ft < 4; ++ft)
            wfk[ft] = *(const bf16x8*)&W1t[(featBase + ft * 16 + lr) * D + kt * 32 + lk * 8];
        bf16x8 mf[4];
#pragma unroll
        for (int mt = 0; mt < 4; ++mt)
            mf[mt] = *(const bf16x8*)&m_bf[nIdx[mt] * D + kt * 32 + lk * 8];
#pragma unroll
        for (int ft = 0; ft < 4; ++ft)
#pragma unroll
            for (int mt = 0; mt < 4; ++mt)
                acc[ft][mt] = __builtin_amdgcn_mfma_f32_16x16x32_bf16(wfk[ft], mf[mt],
                                                                      acc[ft][mt], 0, 0, 0);
    }

    // ---- bias + LeakyReLU + BN -> bf16 -> LDS (swizzled) ----
#pragma unroll
    for (int ft = 0; ft < 4; ++ft) {
        int f0 = featBase + ft * 16 + lk * 4;
#pragma unroll
        for (int mt = 0; mt < 4; ++mt) {
            int nl = nlBase + mt * 16 + lr;
            short4 pk;
#pragma unroll
            for (int r = 0; r < 4; ++r) {
                float v = acc[ft][mt][r] + sB1[f0 + r];
                v = (v > 0.f) ? v : NEG_SLOPE * v;
                v = v * sSc[f0 + r] + sSb[f0 + r];
                ((short*)&pk)[r] = f2bf(v);
            }
            int byteoff = nl * 256 + f0 * 2;
            byteoff ^= (nl & 7) << 4;
            *(short4*)((char*)sy + byteoff) = pk;
        }
    }
    __syncthreads();

    // ---- GEMM2 ----
#pragma unroll
    for (int ft = 0; ft < 4; ++ft)
#pragma unroll
        for (int mt = 0; mt < 4; ++mt)
            acc[ft][mt] = (f32x4)(0.0f);

#pragma unroll
    for (int kt = 0; kt < 4; ++kt) {
        bf16x8 wfk[4];
#pragma unroll
        for (int ft = 0; ft < 4; ++ft)
            wfk[ft] = *(const bf16x8*)&W2t[(featBase + ft * 16 + lr) * D + kt * 32 + lk * 8];
        bf16x8 yf[4];
#pragma unroll
        for (int mt = 0; mt < 4; ++mt) {
            int nl = nlBase + mt * 16 + lr;
            int byteoff = nl * 256 + kt * 64 + lk * 16;
            byteoff ^= (nl & 7) << 4;
            yf[mt] = *(const bf16x8*)((char*)sy + byteoff);
        }
#pragma unroll
        for (int ft = 0; ft < 4; ++ft)
#pragma unroll
            for (int mt = 0; mt < 4; ++mt)
                acc[ft][mt] = __builtin_amdgcn_mfma_f32_16x16x32_bf16(wfk[ft], yf[mt],
                                                                      acc[ft][mt], 0, 0, 0);
    }

    if (!FUSE_FC) {
        // ---- bias + LeakyReLU + gproj add -> bf16 store ----
#pragma unroll
        for (int mt = 0; mt < 4; ++mt) {
            int node = nodeBase + mt * 16 + lr;
            if (node >= N_NODES) continue;
            int bid = batch[node];
#pragma unroll
            for (int ft = 0; ft < 4; ++ft) {
                int f0 = featBase + ft * 16 + lk * 4;
                const float4 gp = *(const float4*)&gproj[bid * D + f0];
                float v0 = acc[ft][mt][0] + sB2[f0 + 0]; v0 = (v0 > 0.f) ? v0 : NEG_SLOPE * v0; v0 += gp.x;
                float v1 = acc[ft][mt][1] + sB2[f0 + 1]; v1 = (v1 > 0.f) ? v1 : NEG_SLOPE * v1; v1 += gp.y;
                float v2 = acc[ft][mt][2] + sB2[f0 + 2]; v2 = (v2 > 0.f) ? v2 : NEG_SLOPE * v2; v2 += gp.z;
                float v3 = acc[ft][mt][3] + sB2[f0 + 3]; v3 = (v3 > 0.f) ? v3 : NEG_SLOPE * v3; v3 += gp.w;
                short4 pk;
                pk.x = f2bf(v0); pk.y = f2bf(v1); pk.z = f2bf(v2); pk.w = f2bf(v3);
                *(short4*)&outb[node * D + f0] = pk;
            }
        }
        return;
    }

    // ---- FUSE_FC: h -> LDS (swizzled), then GEMM3 with fcW ----
    __syncthreads();  // all waves done reading sy in GEMM2 before overwrite
#pragma unroll
    for (int ft = 0; ft < 4; ++ft) {
        int f0 = featBase + ft * 16 + lk * 4;
#pragma unroll
        for (int mt = 0; mt < 4; ++mt) {
            int nl = nlBase + mt * 16 + lr;
            int bid = batch[nIdx[mt]];
            const float4 gp = *(const float4*)&gproj[bid * D + f0];
            short4 pk;
            float v0 = acc[ft][mt][0] + sB2[f0 + 0]; v0 = (v0 > 0.f) ? v0 : NEG_SLOPE * v0; v0 += gp.x;
            float v1 = acc[ft][mt][1] + sB2[f0 + 1]; v1 = (v1 > 0.f) ? v1 : NEG_SLOPE * v1; v1 += gp.y;
            float v2 = acc[ft][mt][2] + sB2[f0 + 2]; v2 = (v2 > 0.f) ? v2 : NEG_SLOPE * v2; v2 += gp.z;
            float v3 = acc[ft][mt][3] + sB2[f0 + 3]; v3 = (v3 > 0.f) ? v3 : NEG_SLOPE * v3; v3 += gp.w;
            pk.x = f2bf(v0); pk.y = f2bf(v1); pk.z = f2bf(v2); pk.w = f2bf(v3);
            int byteoff = nl * 256 + f0 * 2;
            byteoff ^= (nl & 7) << 4;
            *(short4*)((char*)sy + byteoff) = pk;
        }
    }
    __syncthreads();

#pragma unroll
    for (int ft = 0; ft < 4; ++ft)
#pragma unroll
        for (int mt = 0; mt < 4; ++mt)
            acc[ft][mt] = (f32x4)(0.0f);

#pragma unroll
    for (int kt = 0; kt < 4; ++kt) {
        bf16x8 wfk[4];
#pragma unroll
        for (int ft = 0; ft < 4; ++ft)
            wfk[ft] = *(const bf16x8*)&Wft[(featBase + ft * 16 + lr) * D + kt * 32 + lk * 8];
        bf16x8 hf[4];
#pragma unroll
        for (int mt = 0; mt < 4; ++mt) {
            int nl = nlBase + mt * 16 + lr;
            int byteoff = nl * 256 + kt * 64 + lk * 16;
            byteoff ^= (nl & 7) << 4;
            hf[mt] = *(const bf16x8*)((char*)sy + byteoff);
        }
#pragma unroll
        for (int ft = 0; ft < 4; ++ft)
#pragma unroll
            for (int mt = 0; mt < 4; ++mt)
                acc[ft][mt] = __builtin_amdgcn_mfma_f32_16x16x32_bf16(wfk[ft], hf[mt],
                                                                      acc[ft][mt], 0, 0, 0);
    }

#pragma unroll
    for (int mt = 0; mt < 4; ++mt) {
        int node = nodeBase + mt * 16 + lr;
        if (node >= N_NODES) continue;
#pragma unroll
        for (int ft = 0; ft < 4; ++ft) {
            int f0 = featBase + ft * 16 + lk * 4;
            float4 o;
            o.x = acc[ft][mt][0] + sFC[f0 + 0];
            o.y = acc[ft][mt][1] + sFC[f0 + 1];
            o.z = acc[ft][mt][2] + sFC[f0 + 2];
            o.w = acc[ft][mt][3] + sFC[f0 + 3];
            *(float4*)&outf[node * D + f0] = o;
        }
    }
}

// ---------------- launch ----------------

extern "C" void kernel_launch(void* const* d_in, const int* in_sizes, int n_in,
                              void* d_out, int out_size, void* d_ws, size_t ws_size,
                              hipStream_t stream) {
    const float* x = (const float*)d_in[0];
    const int* ei = (const int*)d_in[1];
    const int* src = ei;
    const int* dst = ei + N_EDGES;
    const int* batch = (const int*)d_in[2];
    const float* gs = (const float*)d_in[3];
    const float* W1s = (const float*)d_in[4];
    const float* b1s = (const float*)d_in[5];
    const float* gammas = (const float*)d_in[6];
    const float* betas = (const float*)d_in[7];
    const float* means = (const float*)d_in[8];
    const float* vars = (const float*)d_in[9];
    const float* W2s = (const float*)d_in[10];
    const float* b2s = (const float*)d_in[11];
    const float* statWs = (const float*)d_in[12];
    const float* statBs = (const float*)d_in[13];
    const float* fcW = (const float*)d_in[14];
    const float* fcB = (const float*)d_in[15];
    float* out = (float*)d_out;

    char* ws = (char*)d_ws;
    auto alloc = [&](size_t bytes) {
        char* p = ws;
        ws += (bytes + 255) / 256 * 256;
        return p;
    };
    int* deg = (int*)alloc(N_NODES * sizeof(int));
    int* incl = (int*)alloc(N_NODES * sizeof(int));
    int* bsum = (int*)alloc(64 * sizeof(int));
    int* start = (int*)alloc((N_NODES + 1) * sizeof(int));
    int* cursor = (int*)alloc(N_NODES * sizeof(int));
    int* csr_src = (int*)alloc(N_EDGES * sizeof(int));
    int* bucket_cnt = (int*)alloc(NB * sizeof(int));
    int2* bucketbuf = (int2*)alloc((size_t)NB * BCAP * sizeof(int2));
    float* gproj = (float*)alloc((size_t)L_LAYERS * B_GRAPHS * D * sizeof(float));
    short* wt = (short*)alloc((size_t)7 * D * D * sizeof(short));
    short* xb = (short*)alloc((size_t)N_NODES * D * sizeof(short));
    short* hb = (short*)alloc((size_t)N_NODES * D * sizeof(short));
    short* m_bf = (short*)alloc((size_t)N_NODES * D * sizeof(short));

    const int nscan = (N_NODES + 2047) / 2048;

    // CSR build, bucketed
    zero_n_kernel<<<1, 256, 0, stream>>>(bucket_cnt, NB);
    bucketA_kernel<<<N_EDGES / EPB, 256, 0, stream>>>(src, dst, bucket_cnt, bucketbuf);
    bucketB1_kernel<<<NB, 256, 0, stream>>>(bucket_cnt, bucketbuf, deg);
    scan1_kernel<<<nscan, 256, 0, stream>>>(deg, incl, bsum);
    scan2_kernel<<<1, 64, 0, stream>>>(bsum, nscan);
    scan3_kernel<<<(N_NODES + 255) / 256, 256, 0, stream>>>(deg, incl, bsum, start, cursor);
    bucketB2_kernel<<<NB, 256, 0, stream>>>(bucket_cnt, bucketbuf, cursor, csr_src);

    gproj_kernel<<<dim3(B_GRAPHS, L_LAYERS), D, 0, stream>>>(gs, statWs, statBs, gproj);
    wconv_kernel<<<dim3(64, 7), 256, 0, stream>>>(W1s, W2s, fcW, wt);
    xconv_kernel<<<(N_NODES * D / 8 + 255) / 256, 256, 0, stream>>>(x, xb);

    const int agg_blocks = N_NODES / 16;
    const int mlp_blocks = (N_NODES + 127) / 128;

    // layer 0
    agg_kernel<<<agg_blocks, 256, 0, stream>>>(xb, start, csr_src, m_bf);
    mlp_mfma_kernel<false><<<mlp_blocks, 256, 0, stream>>>(
        m_bf, wt + 0 * D * D, b1s + 0 * D, gammas + 0 * D, betas + 0 * D, means + 0 * D,
        vars + 0 * D, wt + 3 * D * D, b2s + 0 * D, gproj + 0 * B_GRAPHS * D, batch,
        nullptr, nullptr, nullptr, hb);
    // layer 1
    agg_kernel<<<agg_blocks, 256, 0, stream>>>(hb, start, csr_src, m_bf);
    mlp_mfma_kernel<false><<<mlp_blocks, 256, 0, stream>>>(
        m_bf, wt + 1 * D * D, b1s + 1 * D, gammas + 1 * D, betas + 1 * D, means + 1 * D,
        vars + 1 * D, wt + 4 * D * D, b2s + 1 * D, gproj + 1 * B_GRAPHS * D, batch,
        nullptr, nullptr, nullptr, hb);
    // layer 2 + fused fc_out
    agg_kernel<<<agg_blocks, 256, 0, stream>>>(hb, start, csr_src, m_bf);
    mlp_mfma_kernel<true><<<mlp_blocks, 256, 0, stream>>>(
        m_bf, wt + 2 * D * D, b1s + 2 * D, gammas + 2 * D, betas + 2 * D, means + 2 * D,
        vars + 2 * D, wt + 5 * D * D, b2s + 2 * D, gproj + 2 * B_GRAPHS * D, batch,
        wt + 6 * D * D, fcB, out, nullptr);
}

// Round 6
// 380.498 us; speedup vs baseline: 2.7085x; 1.0356x over previous
//
#include <hip/hip_runtime.h>
#include <math.h>

#define N_NODES 100000
#define N_EDGES 1600000
#define D 128
#define L_LAYERS 3
#define P_STATS 7
#define B_GRAPHS 64
#define BN_EPS 1e-5f
#define NEG_SLOPE 0.2f

#define NB 196        // buckets of 512 dst nodes
#define BCAP 10240
#define EPB 6400

typedef __attribute__((ext_vector_type(8))) short bf16x8;
typedef __attribute__((ext_vector_type(4))) float f32x4;

static __device__ __forceinline__ short f2bf(float f) {
    union { float f; unsigned u; } v;
    v.f = f;
    unsigned r = v.u + 0x7fffu + ((v.u >> 16) & 1u);  // RNE
    return (short)(r >> 16);
}

static __device__ __forceinline__ float bf2f(short s) {
    union { unsigned u; float f; } v;
    v.u = ((unsigned)(unsigned short)s) << 16;
    return v.f;
}

// ---------------- CSR build (bucketed) ----------------

__global__ void zero_n_kernel(int* __restrict__ p, int n) {
    int i = blockIdx.x * blockDim.x + threadIdx.x;
    if (i < n) p[i] = 0;
}

__global__ __launch_bounds__(256) void bucketA_kernel(const int* __restrict__ src,
                                                      const int* __restrict__ dst,
                                                      int* __restrict__ bucket_cnt,
                                                      int2* __restrict__ bucketbuf) {
    __shared__ int s_src[EPB];
    __shared__ int s_dst[EPB];
    __shared__ int hist[NB], base[NB], loc[NB];
    const int tid = threadIdx.x;
    const int e0 = blockIdx.x * EPB;
    for (int i = tid; i < NB; i += 256) { hist[i] = 0; loc[i] = 0; }
    __syncthreads();
    for (int i = tid; i < EPB; i += 256) {
        int s = src[e0 + i];
        int d = dst[e0 + i];
        s_src[i] = s;
        s_dst[i] = d;
        atomicAdd(&hist[d >> 9], 1);
    }
    __syncthreads();
    for (int i = tid; i < NB; i += 256)
        base[i] = hist[i] ? atomicAdd(&bucket_cnt[i], hist[i]) : 0;
    __syncthreads();
    for (int i = tid; i < EPB; i += 256) {
        int d = s_dst[i];
        int b = d >> 9;
        int off = atomicAdd(&loc[b], 1);
        int idx = base[b] + off;
        if (idx < BCAP) bucketbuf[(size_t)b * BCAP + idx] = make_int2(s_src[i], d);
    }
}

__global__ __launch_bounds__(256) void bucketB1_kernel(const int* __restrict__ bucket_cnt,
                                                       const int2* __restrict__ bucketbuf,
                                                       int* __restrict__ deg) {
    __shared__ int hist[512];
    const int b = blockIdx.x;
    for (int i = threadIdx.x; i < 512; i += 256) hist[i] = 0;
    __syncthreads();
    int cnt = min(bucket_cnt[b], BCAP);
    for (int i = threadIdx.x; i < cnt; i += 256) {
        int d = bucketbuf[(size_t)b * BCAP + i].y;
        atomicAdd(&hist[d & 511], 1);
    }
    __syncthreads();
    int nbase = b << 9;
    for (int i = threadIdx.x; i < 512; i += 256) {
        int node = nbase + i;
        if (node < N_NODES) deg[node] = hist[i];
    }
}

__global__ __launch_bounds__(256) void bucketB2_kernel(const int* __restrict__ bucket_cnt,
                                                       const int2* __restrict__ bucketbuf,
                                                       int* __restrict__ cursor,
                                                       int* __restrict__ csr_src) {
    const int b = blockIdx.x;
    int cnt = min(bucket_cnt[b], BCAP);
    for (int i = threadIdx.x; i < cnt; i += 256) {
        int2 p = bucketbuf[(size_t)b * BCAP + i];
        int pos = atomicAdd(&cursor[p.y], 1);
        csr_src[pos] = p.x;
    }
}

// ---------------- scans ----------------

__global__ void scan1_kernel(const int* __restrict__ deg, int* __restrict__ incl,
                             int* __restrict__ bsum) {
    __shared__ int s[256];
    const int tid = threadIdx.x;
    const int base = blockIdx.x * 2048;
    int v[8];
    int sum = 0;
    const int idx0 = base + tid * 8;
#pragma unroll
    for (int i = 0; i < 8; ++i) {
        int idx = idx0 + i;
        int d = (idx < N_NODES) ? deg[idx] : 0;
        sum += d;
        v[i] = sum;
    }
    s[tid] = sum;
    __syncthreads();
    for (int off = 1; off < 256; off <<= 1) {
        int t = (tid >= off) ? s[tid - off] : 0;
        __syncthreads();
        s[tid] += t;
        __syncthreads();
    }
    int prev = (tid > 0) ? s[tid - 1] : 0;
#pragma unroll
    for (int i = 0; i < 8; ++i) {
        int idx = idx0 + i;
        if (idx < N_NODES) incl[idx] = v[i] + prev;
    }
    if (tid == 255) bsum[blockIdx.x] = s[255];
}

__global__ void scan2_kernel(int* __restrict__ bsum, int nb) {
    if (threadIdx.x == 0 && blockIdx.x == 0) {
        int run = 0;
        for (int i = 0; i < nb; ++i) { int t = bsum[i]; bsum[i] = run; run += t; }
    }
}

__global__ void scan3_kernel(const int* __restrict__ deg, const int* __restrict__ incl,
                             const int* __restrict__ bsum, int* __restrict__ start,
                             int* __restrict__ cursor) {
    int i = blockIdx.x * blockDim.x + threadIdx.x;
    if (i < N_NODES) {
        int inc = incl[i] + bsum[i >> 11];
        int st = inc - deg[i];
        start[i] = st;
        cursor[i] = st;
    }
    if (i == 0) start[N_NODES] = N_EDGES;
}

// ---------------- per-graph stat projections ----------------
__global__ void gproj_kernel(const float* __restrict__ gs, const float* __restrict__ statWs,
                             const float* __restrict__ statBs, float* __restrict__ gproj) {
    int b = blockIdx.x;
    int l = blockIdx.y;
    int j = threadIdx.x;
    float acc = statBs[l * D + j];
#pragma unroll
    for (int p = 0; p < P_STATS; ++p) {
        float g = gs[b * P_STATS + p];
        if (g != g) g = -100.0f;
        acc += g * statWs[(l * P_STATS + p) * D + j];
    }
    gproj[(l * B_GRAPHS + b) * D + j] = acc;
}

// ---------------- weight convert: W[k][n] f32 -> Wt[n][k] bf16 ----------------
__global__ void wconv_kernel(const float* __restrict__ W1s, const float* __restrict__ W2s,
                             const float* __restrict__ fcW, short* __restrict__ wt) {
    int mid = blockIdx.y;
    const float* src = (mid < 3) ? (W1s + mid * D * D)
                                 : ((mid < 6) ? (W2s + (mid - 3) * D * D) : fcW);
    short* dstm = wt + mid * D * D;
    int i = blockIdx.x * 256 + threadIdx.x;
    int k = i >> 7, n = i & 127;
    dstm[n * D + k] = f2bf(src[i]);
}

// ---------------- x f32 -> bf16 ----------------
__global__ __launch_bounds__(256) void xconv_kernel(const float* __restrict__ x,
                                                    short* __restrict__ xb) {
    int i = blockIdx.x * 256 + threadIdx.x;
    const float4* x4 = (const float4*)x;
    float4 a = x4[i * 2], b = x4[i * 2 + 1];
    short s[8];
    s[0] = f2bf(a.x); s[1] = f2bf(a.y); s[2] = f2bf(a.z); s[3] = f2bf(a.w);
    s[4] = f2bf(b.x); s[5] = f2bf(b.y); s[6] = f2bf(b.z); s[7] = f2bf(b.w);
    *(bf16x8*)&xb[i * 8] = *(bf16x8*)s;
}

// ---------------- fused agg + MLP (+ optional fc_out) ----------------
// Block: 128 nodes x 128 features, 256 threads = 4 waves.
// Phase 0: gather-aggregate m = h + sum h[src] directly into swizzled LDS.
// Then GEMM1 -> LReLU/BN -> LDS -> GEMM2 -> [store bf16 h] or
// [LReLU+gproj -> LDS -> GEMM3(fcW) -> store f32 out].
template <bool FUSE_FC>
__global__ __launch_bounds__(256, 4) void mlp_fused_kernel(
    const short* __restrict__ h_in,   // [N][128] bf16 (gather source)
    const int* __restrict__ start, const int* __restrict__ csr_src,
    const short* __restrict__ W1t,
    const float* __restrict__ b1,
    const float* __restrict__ gamma, const float* __restrict__ beta,
    const float* __restrict__ mean, const float* __restrict__ var,
    const short* __restrict__ W2t,
    const float* __restrict__ b2,
    const float* __restrict__ gproj, const int* __restrict__ batch,
    const short* __restrict__ Wft, const float* __restrict__ fcb,
    float* __restrict__ outf, short* __restrict__ outb) {
    __shared__ short sy[128 * 128];  // 32KB, XOR-swizzled rows
    __shared__ float sB1[128], sSc[128], sSb[128], sB2[128], sFC[128];

    const int tid = threadIdx.x;
    const int wid = tid >> 6;
    const int lane = tid & 63;
    const int lr = lane & 15;
    const int lk = lane >> 4;

    if (tid < 128) {
        sB1[tid] = b1[tid];
        float sc = gamma[tid] * rsqrtf(var[tid] + BN_EPS);
        sSc[tid] = sc;
        sSb[tid] = beta[tid] - mean[tid] * sc;
        sB2[tid] = b2[tid];
        if (FUSE_FC) sFC[tid] = fcb[tid];
    }

    // ---- Phase 0: gather-aggregate into LDS (swizzled m tile) ----
    {
        const bf16x8* h8 = (const bf16x8*)h_in;
        const int c8 = lane & 15;
        const int sub = lane >> 4;  // 0..3
#pragma unroll
        for (int it = 0; it < 8; ++it) {
            int nl = wid * 32 + it * 4 + sub;          // 0..127
            int node = blockIdx.x * 128 + nl;
            float acc[8];
            if (node < N_NODES) {
                bf16x8 own = h8[node * 16 + c8];
#pragma unroll
                for (int i = 0; i < 8; ++i) acc[i] = bf2f(own[i]);
                int s = start[node];
                int e = start[node + 1];
                int k = s;
                for (; k + 4 <= e; k += 4) {
                    int sn0 = csr_src[k];
                    int sn1 = csr_src[k + 1];
                    int sn2 = csr_src[k + 2];
                    int sn3 = csr_src[k + 3];
                    bf16x8 v0 = h8[sn0 * 16 + c8];
                    bf16x8 v1 = h8[sn1 * 16 + c8];
                    bf16x8 v2 = h8[sn2 * 16 + c8];
                    bf16x8 v3 = h8[sn3 * 16 + c8];
#pragma unroll
                    for (int i = 0; i < 8; ++i) acc[i] += bf2f(v0[i]);
#pragma unroll
                    for (int i = 0; i < 8; ++i) acc[i] += bf2f(v1[i]);
#pragma unroll
                    for (int i = 0; i < 8; ++i) acc[i] += bf2f(v2[i]);
#pragma unroll
                    for (int i = 0; i < 8; ++i) acc[i] += bf2f(v3[i]);
                }
                for (; k < e; ++k) {
                    int sn0 = csr_src[k];
                    bf16x8 v0 = h8[sn0 * 16 + c8];
#pragma unroll
                    for (int i = 0; i < 8; ++i) acc[i] += bf2f(v0[i]);
                }
            } else {
#pragma unroll
                for (int i = 0; i < 8; ++i) acc[i] = 0.f;
            }
            short pk[8];
#pragma unroll
            for (int i = 0; i < 8; ++i) pk[i] = f2bf(acc[i]);
            int byteoff = nl * 256 + c8 * 16;
            byteoff ^= (nl & 7) << 4;
            *(bf16x8*)((char*)sy + byteoff) = *(bf16x8*)pk;
        }
    }
    __syncthreads();

    const int nodeBase = blockIdx.x * 128 + (wid & 1) * 64;
    const int featBase = (wid >> 1) * 64;
    const int nlBase = (wid & 1) * 64;

    int nIdx[4];
#pragma unroll
    for (int mt = 0; mt < 4; ++mt) {
        int n = nodeBase + mt * 16 + lr;
        nIdx[mt] = (n < N_NODES) ? n : (N_NODES - 1);
    }

    f32x4 acc[4][4];
#pragma unroll
    for (int ft = 0; ft < 4; ++ft)
#pragma unroll
        for (int mt = 0; mt < 4; ++mt)
            acc[ft][mt] = (f32x4)(0.0f);

    // ---- GEMM1 (m from LDS) ----
#pragma unroll
    for (int kt = 0; kt < 4; ++kt) {
        bf16x8 wfk[4];
#pragma unroll
        for (int ft = 0; ft < 4; ++ft)
            wfk[ft] = *(const bf16x8*)&W1t[(featBase + ft * 16 + lr) * D + kt * 32 + lk * 8];
        bf16x8 mf[4];
#pragma unroll
        for (int mt = 0; mt < 4; ++mt) {
            int nl = nlBase + mt * 16 + lr;
            int byteoff = nl * 256 + kt * 64 + lk * 16;
            byteoff ^= (nl & 7) << 4;
            mf[mt] = *(const bf16x8*)((char*)sy + byteoff);
        }
#pragma unroll
        for (int ft = 0; ft < 4; ++ft)
#pragma unroll
            for (int mt = 0; mt < 4; ++mt)
                acc[ft][mt] = __builtin_amdgcn_mfma_f32_16x16x32_bf16(wfk[ft], mf[mt],
                                                                      acc[ft][mt], 0, 0, 0);
    }
    __syncthreads();  // all waves done reading m before Y overwrite

    // ---- bias + LeakyReLU + BN -> bf16 -> LDS (swizzled) ----
#pragma unroll
    for (int ft = 0; ft < 4; ++ft) {
        int f0 = featBase + ft * 16 + lk * 4;
#pragma unroll
        for (int mt = 0; mt < 4; ++mt) {
            int nl = nlBase + mt * 16 + lr;
            short4 pk;
#pragma unroll
            for (int r = 0; r < 4; ++r) {
                float v = acc[ft][mt][r] + sB1[f0 + r];
                v = (v > 0.f) ? v : NEG_SLOPE * v;
                v = v * sSc[f0 + r] + sSb[f0 + r];
                ((short*)&pk)[r] = f2bf(v);
            }
            int byteoff = nl * 256 + f0 * 2;
            byteoff ^= (nl & 7) << 4;
            *(short4*)((char*)sy + byteoff) = pk;
        }
    }
    __syncthreads();

    // ---- GEMM2 ----
#pragma unroll
    for (int ft = 0; ft < 4; ++ft)
#pragma unroll
        for (int mt = 0; mt < 4; ++mt)
            acc[ft][mt] = (f32x4)(0.0f);

#pragma unroll
    for (int kt = 0; kt < 4; ++kt) {
        bf16x8 wfk[4];
#pragma unroll
        for (int ft = 0; ft < 4; ++ft)
            wfk[ft] = *(const bf16x8*)&W2t[(featBase + ft * 16 + lr) * D + kt * 32 + lk * 8];
        bf16x8 yf[4];
#pragma unroll
        for (int mt = 0; mt < 4; ++mt) {
            int nl = nlBase + mt * 16 + lr;
            int byteoff = nl * 256 + kt * 64 + lk * 16;
            byteoff ^= (nl & 7) << 4;
            yf[mt] = *(const bf16x8*)((char*)sy + byteoff);
        }
#pragma unroll
        for (int ft = 0; ft < 4; ++ft)
#pragma unroll
            for (int mt = 0; mt < 4; ++mt)
                acc[ft][mt] = __builtin_amdgcn_mfma_f32_16x16x32_bf16(wfk[ft], yf[mt],
                                                                      acc[ft][mt], 0, 0, 0);
    }

    if (!FUSE_FC) {
        // ---- bias + LeakyReLU + gproj add -> bf16 store ----
#pragma unroll
        for (int mt = 0; mt < 4; ++mt) {
            int node = nodeBase + mt * 16 + lr;
            if (node >= N_NODES) continue;
            int bid = batch[node];
#pragma unroll
            for (int ft = 0; ft < 4; ++ft) {
                int f0 = featBase + ft * 16 + lk * 4;
                const float4 gp = *(const float4*)&gproj[bid * D + f0];
                float v0 = acc[ft][mt][0] + sB2[f0 + 0]; v0 = (v0 > 0.f) ? v0 : NEG_SLOPE * v0; v0 += gp.x;
                float v1 = acc[ft][mt][1] + sB2[f0 + 1]; v1 = (v1 > 0.f) ? v1 : NEG_SLOPE * v1; v1 += gp.y;
                float v2 = acc[ft][mt][2] + sB2[f0 + 2]; v2 = (v2 > 0.f) ? v2 : NEG_SLOPE * v2; v2 += gp.z;
                float v3 = acc[ft][mt][3] + sB2[f0 + 3]; v3 = (v3 > 0.f) ? v3 : NEG_SLOPE * v3; v3 += gp.w;
                short4 pk;
                pk.x = f2bf(v0); pk.y = f2bf(v1); pk.z = f2bf(v2); pk.w = f2bf(v3);
                *(short4*)&outb[node * D + f0] = pk;
            }
        }
        return;
    }

    // ---- FUSE_FC: h -> LDS (swizzled), then GEMM3 with fcW ----
    __syncthreads();  // all waves done reading sy in GEMM2 before overwrite
#pragma unroll
    for (int ft = 0; ft < 4; ++ft) {
        int f0 = featBase + ft * 16 + lk * 4;
#pragma unroll
        for (int mt = 0; mt < 4; ++mt) {
            int nl = nlBase + mt * 16 + lr;
            int bid = batch[nIdx[mt]];
            const float4 gp = *(const float4*)&gproj[bid * D + f0];
            short4 pk;
            float v0 = acc[ft][mt][0] + sB2[f0 + 0]; v0 = (v0 > 0.f) ? v0 : NEG_SLOPE * v0; v0 += gp.x;
            float v1 = acc[ft][mt][1] + sB2[f0 + 1]; v1 = (v1 > 0.f) ? v1 : NEG_SLOPE * v1; v1 += gp.y;
            float v2 = acc[ft][mt][2] + sB2[f0 + 2]; v2 = (v2 > 0.f) ? v2 : NEG_SLOPE * v2; v2 += gp.z;
            float v3 = acc[ft][mt][3] + sB2[f0 + 3]; v3 = (v3 > 0.f) ? v3 : NEG_SLOPE * v3; v3 += gp.w;
            pk.x = f2bf(v0); pk.y = f2bf(v1); pk.z = f2bf(v2); pk.w = f2bf(v3);
            int byteoff = nl * 256 + f0 * 2;
            byteoff ^= (nl & 7) << 4;
            *(short4*)((char*)sy + byteoff) = pk;
        }
    }
    __syncthreads();

#pragma unroll
    for (int ft = 0; ft < 4; ++ft)
#pragma unroll
        for (int mt = 0; mt < 4; ++mt)
            acc[ft][mt] = (f32x4)(0.0f);

#pragma unroll
    for (int kt = 0; kt < 4; ++kt) {
        bf16x8 wfk[4];
#pragma unroll
        for (int ft = 0; ft < 4; ++ft)
            wfk[ft] = *(const bf16x8*)&Wft[(featBase + ft * 16 + lr) * D + kt * 32 + lk * 8];
        bf16x8 hf[4];
#pragma unroll
        for (int mt = 0; mt < 4; ++mt) {
            int nl = nlBase + mt * 16 + lr;
            int byteoff = nl * 256 + kt * 64 + lk * 16;
            byteoff ^= (nl & 7) << 4;
            hf[mt] = *(const bf16x8*)((char*)sy + byteoff);
        }
#pragma unroll
        for (int ft = 0; ft < 4; ++ft)
#pragma unroll
            for (int mt = 0; mt < 4; ++mt)
                acc[ft][mt] = __builtin_amdgcn_mfma_f32_16x16x32_bf16(wfk[ft], hf[mt],
                                                                      acc[ft][mt], 0, 0, 0);
    }

#pragma unroll
    for (int mt = 0; mt < 4; ++mt) {
        int node = nodeBase + mt * 16 + lr;
        if (node >= N_NODES) continue;
#pragma unroll
        for (int ft = 0; ft < 4; ++ft) {
            int f0 = featBase + ft * 16 + lk * 4;
            float4 o;
            o.x = acc[ft][mt][0] + sFC[f0 + 0];
            o.y = acc[ft][mt][1] + sFC[f0 + 1];
            o.z = acc[ft][mt][2] + sFC[f0 + 2];
            o.w = acc[ft][mt][3] + sFC[f0 + 3];
            *(float4*)&outf[node * D + f0] = o;
        }
    }
}

// ---------------- launch ----------------

extern "C" void kernel_launch(void* const* d_in, const int* in_sizes, int n_in,
                              void* d_out, int out_size, void* d_ws, size_t ws_size,
                              hipStream_t stream) {
    const float* x = (const float*)d_in[0];
    const int* ei = (const int*)d_in[1];
    const int* src = ei;
    const int* dst = ei + N_EDGES;
    const int* batch = (const int*)d_in[2];
    const float* gs = (const float*)d_in[3];
    const float* W1s = (const float*)d_in[4];
    const float* b1s = (const float*)d_in[5];
    const float* gammas = (const float*)d_in[6];
    const float* betas = (const float*)d_in[7];
    const float* means = (const float*)d_in[8];
    const float* vars = (const float*)d_in[9];
    const float* W2s = (const float*)d_in[10];
    const float* b2s = (const float*)d_in[11];
    const float* statWs = (const float*)d_in[12];
    const float* statBs = (const float*)d_in[13];
    const float* fcW = (const float*)d_in[14];
    const float* fcB = (const float*)d_in[15];
    float* out = (float*)d_out;

    char* ws = (char*)d_ws;
    auto alloc = [&](size_t bytes) {
        char* p = ws;
        ws += (bytes + 255) / 256 * 256;
        return p;
    };
    int* deg = (int*)alloc(N_NODES * sizeof(int));
    int* incl = (int*)alloc(N_NODES * sizeof(int));
    int* bsum = (int*)alloc(64 * sizeof(int));
    int* start = (int*)alloc((N_NODES + 1) * sizeof(int));
    int* cursor = (int*)alloc(N_NODES * sizeof(int));
    int* csr_src = (int*)alloc(N_EDGES * sizeof(int));
    int* bucket_cnt = (int*)alloc(NB * sizeof(int));
    int2* bucketbuf = (int2*)alloc((size_t)NB * BCAP * sizeof(int2));
    float* gproj = (float*)alloc((size_t)L_LAYERS * B_GRAPHS * D * sizeof(float));
    short* wt = (short*)alloc((size_t)7 * D * D * sizeof(short));
    short* xb = (short*)alloc((size_t)N_NODES * D * sizeof(short));
    short* hb1 = (short*)alloc((size_t)N_NODES * D * sizeof(short));
    short* hb2 = (short*)alloc((size_t)N_NODES * D * sizeof(short));

    const int nscan = (N_NODES + 2047) / 2048;

    // CSR build, bucketed
    zero_n_kernel<<<1, 256, 0, stream>>>(bucket_cnt, NB);
    bucketA_kernel<<<N_EDGES / EPB, 256, 0, stream>>>(src, dst, bucket_cnt, bucketbuf);
    bucketB1_kernel<<<NB, 256, 0, stream>>>(bucket_cnt, bucketbuf, deg);
    scan1_kernel<<<nscan, 256, 0, stream>>>(deg, incl, bsum);
    scan2_kernel<<<1, 64, 0, stream>>>(bsum, nscan);
    scan3_kernel<<<(N_NODES + 255) / 256, 256, 0, stream>>>(deg, incl, bsum, start, cursor);
    bucketB2_kernel<<<NB, 256, 0, stream>>>(bucket_cnt, bucketbuf, cursor, csr_src);

    gproj_kernel<<<dim3(B_GRAPHS, L_LAYERS), D, 0, stream>>>(gs, statWs, statBs, gproj);
    wconv_kernel<<<dim3(64, 7), 256, 0, stream>>>(W1s, W2s, fcW, wt);
    xconv_kernel<<<(N_NODES * D / 8 + 255) / 256, 256, 0, stream>>>(x, xb);

    const int mlp_blocks = (N_NODES + 127) / 128;

    // layer 0: xb -> hb1
    mlp_fused_kernel<false><<<mlp_blocks, 256, 0, stream>>>(
        xb, start, csr_src, wt + 0 * D * D, b1s + 0 * D, gammas + 0 * D, betas + 0 * D,
        means + 0 * D, vars + 0 * D, wt + 3 * D * D, b2s + 0 * D, gproj + 0 * B_GRAPHS * D,
        batch, nullptr, nullptr, nullptr, hb1);
    // layer 1: hb1 -> hb2
    mlp_fused_kernel<false><<<mlp_blocks, 256, 0, stream>>>(
        hb1, start, csr_src, wt + 1 * D * D, b1s + 1 * D, gammas + 1 * D, betas + 1 * D,
        means + 1 * D, vars + 1 * D, wt + 4 * D * D, b2s + 1 * D, gproj + 1 * B_GRAPHS * D,
        batch, nullptr, nullptr, nullptr, hb2);
    // layer 2 + fused fc_out: hb2 -> out (f32)
    mlp_fused_kernel<true><<<mlp_blocks, 256, 0, stream>>>(
        hb2, start, csr_src, wt + 2 * D * D, b1s + 2 * D, gammas + 2 * D, betas + 2 * D,
        means + 2 * D, vars + 2 * D, wt + 5 * D * D, b2s + 2 * D, gproj + 2 * B_GRAPHS * D,
        batch, wt + 6 * D * D, fcB, out, nullptr);
}